// Round 4
// baseline (49683.228 us; speedup 1.0000x reference)
//
#include <hip/hip_runtime.h>
#include <math.h>

#define HID  1024
#define SEQ  512
#define NB   64
#define DIN0 512

using short8 = __attribute__((ext_vector_type(8))) short;
using f32x4  = __attribute__((ext_vector_type(4))) float;

__device__ __forceinline__ unsigned short f2bf(float f) {
    unsigned int u = __float_as_uint(f);
    u += 0x7fffu + ((u >> 16) & 1u);          // round-to-nearest-even
    return (unsigned short)(u >> 16);
}
__device__ __forceinline__ float sigm_(float x) { return 1.0f / (1.0f + __expf(-x)); }
__device__ __forceinline__ float tanh_(float x) {
    float ax = fabsf(x);
    float e = __expf(-2.0f * ax);
    float t = (1.0f - e) / (1.0f + e);
    return copysignf(t, x);
}
__device__ __forceinline__ short8 pack8(const float* p) {
    float4 f0 = *(const float4*)p;
    float4 f1 = *(const float4*)(p + 4);
    short8 pk;
    pk[0] = (short)f2bf(f0.x); pk[1] = (short)f2bf(f0.y);
    pk[2] = (short)f2bf(f0.z); pk[3] = (short)f2bf(f0.w);
    pk[4] = (short)f2bf(f1.x); pk[5] = (short)f2bf(f1.y);
    pk[6] = (short)f2bf(f1.z); pk[7] = (short)f2bf(f1.w);
    return pk;
}

// Tree grid barrier: 8 sub-counters (one per bid&7 group of 32) -> root -> gen.
// bar layout (u32 idx): [0]=gen, [16]=root, [32 + g*16]=sub_g. Zeroed per call.
// Requires all blocks co-resident: grid=256 = #CUs, 1-block/CU resources.
__device__ __forceinline__ void grid_barrier(unsigned* bar, int bid) {
    __threadfence();                       // release this block's writes (device scope)
    __syncthreads();
    if (threadIdx.x == 0) {
        unsigned* gen  = bar;
        unsigned* root = bar + 16;
        unsigned* sub  = bar + 32 + (bid & 7) * 16;
        unsigned g = __hip_atomic_load(gen, __ATOMIC_RELAXED, __HIP_MEMORY_SCOPE_AGENT);
        if (__hip_atomic_fetch_add(sub, 1u, __ATOMIC_ACQ_REL, __HIP_MEMORY_SCOPE_AGENT) == 31u) {
            __hip_atomic_store(sub, 0u, __ATOMIC_RELAXED, __HIP_MEMORY_SCOPE_AGENT);
            if (__hip_atomic_fetch_add(root, 1u, __ATOMIC_ACQ_REL, __HIP_MEMORY_SCOPE_AGENT) == 7u) {
                __hip_atomic_store(root, 0u, __ATOMIC_RELAXED, __HIP_MEMORY_SCOPE_AGENT);
                __hip_atomic_fetch_add(gen, 1u, __ATOMIC_RELEASE, __HIP_MEMORY_SCOPE_AGENT);
            }
        }
        while (__hip_atomic_load(gen, __ATOMIC_ACQUIRE, __HIP_MEMORY_SCOPE_AGENT) == g)
            __builtin_amdgcn_s_sleep(2);
    }
    __syncthreads();
    __threadfence();                       // acquire side: drop stale cached lines
}

// Persistent fused 2-layer GRU. 256 blocks x 256 thr, one block per CU.
// Block bid: layer = bid>>7, j-slice of 8 = (bid&127)*8. Wave w owns K-quarter,
// holds its weight B-frags in VGPRs for the whole kernel. Per interval i:
// L0 computes t=i, L1 computes t=i-1 (skew), then grid barrier.
__global__ __launch_bounds__(256, 1) void gru_persist(
    const float* __restrict__ x,
    const unsigned short* __restrict__ W0i, const unsigned short* __restrict__ W0h,
    const unsigned short* __restrict__ W1i, const unsigned short* __restrict__ W1h,
    const float* __restrict__ bi0, const float* __restrict__ bh0,
    const float* __restrict__ bi1, const float* __restrict__ bh1,
    float* __restrict__ hf,          // [2 layer][2 parity][64][1024] f32
    unsigned short* __restrict__ hb, // same layout, bf16
    float* __restrict__ out,         // [64][512][1024]
    unsigned* __restrict__ bar)
{
    const int bid   = blockIdx.x;
    const int layer = bid >> 7;
    const int j0    = (bid & 127) << 3;
    const int tid   = threadIdx.x;
    const int l     = tid & 63;
    const int w     = tid >> 6;     // wave id = K-quarter
    const int c     = l & 15;       // frag col / A row
    const int kg    = l >> 4;       // k subgroup

    const int Din  = layer ? HID : DIN0;
    const int Kq   = (Din + HID) >> 2;     // 512 or 384
    const int nkst = Kq >> 5;              // 16 or 12
    const int kq0  = w * Kq;

    const unsigned short* Wi = layer ? W1i : W0i;
    const unsigned short* Wh = layer ? W1h : W0h;
    const float* bi  = layer ? bi1 : bi0;
    const float* bh_ = layer ? bh1 : bh0;

    // ---- one-time: weight B-frags into registers ----
    // n-tile0 packs [r | z] (col<8 -> r row, col>=8 -> z row); n-tile1 = n gate.
    const int row0 = ((c < 8) ? 0 : HID) + j0 + (c & 7);
    const int row1 = 2 * HID + j0 + (c & 7);
    short8 Bw0[16], Bw1[16];
#pragma unroll
    for (int s = 0; s < 16; ++s) {
        if (s < nkst) {
            const int k0 = kq0 + s * 32 + kg * 8;
            const unsigned short *p0, *p1;
            if (k0 < Din) { p0 = Wi + (long)row0 * Din + k0;         p1 = Wi + (long)row1 * Din + k0; }
            else          { p0 = Wh + (long)row0 * HID + (k0 - Din); p1 = Wh + (long)row1 * HID + (k0 - Din); }
            Bw0[s] = *(const short8*)p0;
            Bw1[s] = *(const short8*)p1;
        }
    }

    __shared__ float lds[4][4][3][256];   // [wave][m][rz|nx|nh][16x16 f32] = 48 KB

    for (int i = 0; i <= SEQ; ++i) {
        const int st = layer ? (i - 1) : i;
        if (st >= 0 && st < SEQ) {
            const int rp = st & 1, wp = rp ^ 1;
            const unsigned short* Alo = hb + (long)(0 * 2 + wp) * NB * HID;      // L1: out0(st)
            const unsigned short* Ahi = hb + (long)(layer * 2 + rp) * NB * HID;  // own h(st-1)

            f32x4 acc_rz[4], acc_nx[4], acc_nh[4];
#pragma unroll
            for (int m = 0; m < 4; ++m) {
                acc_rz[m] = (f32x4){0.f, 0.f, 0.f, 0.f};
                acc_nx[m] = (f32x4){0.f, 0.f, 0.f, 0.f};
                acc_nh[m] = (f32x4){0.f, 0.f, 0.f, 0.f};
            }

#pragma unroll
            for (int s = 0; s < 16; ++s) {
                if (s < nkst) {
                    const int kk = kq0 + s * 32 + kg * 8;
                    const bool lo = kk < Din;     // x-side (input) vs h-side region
                    short8 a[4];
#pragma unroll
                    for (int m = 0; m < 4; ++m) {
                        const int b = m * 16 + c;
                        if (layer == 0) {
                            a[m] = lo ? pack8(x + ((long)b * SEQ + st) * DIN0 + kk)
                                      : *(const short8*)(Ahi + (long)b * HID + (kk - DIN0));
                        } else {
                            a[m] = lo ? *(const short8*)(Alo + (long)b * HID + kk)
                                      : *(const short8*)(Ahi + (long)b * HID + (kk - HID));
                        }
                    }
#pragma unroll
                    for (int m = 0; m < 4; ++m)
                        acc_rz[m] = __builtin_amdgcn_mfma_f32_16x16x32_bf16(a[m], Bw0[s], acc_rz[m], 0, 0, 0);
                    if (lo) {
#pragma unroll
                        for (int m = 0; m < 4; ++m)
                            acc_nx[m] = __builtin_amdgcn_mfma_f32_16x16x32_bf16(a[m], Bw1[s], acc_nx[m], 0, 0, 0);
                    } else {
#pragma unroll
                        for (int m = 0; m < 4; ++m)
                            acc_nh[m] = __builtin_amdgcn_mfma_f32_16x16x32_bf16(a[m], Bw1[s], acc_nh[m], 0, 0, 0);
                    }
                }
            }

            // ---- K-quarter partials -> LDS ----
#pragma unroll
            for (int m = 0; m < 4; ++m)
#pragma unroll
                for (int v = 0; v < 4; ++v) {
                    const int rc = (kg * 4 + v) * 16 + c;   // C/D: row=(l>>4)*4+v, col=l&15
                    lds[w][m][0][rc] = acc_rz[m][v];
                    lds[w][m][1][rc] = acc_nx[m][v];
                    lds[w][m][2][rc] = acc_nh[m][v];
                }
            __syncthreads();

            // ---- combine across 4 waves + pointwise (512 items, 2/thread) ----
#pragma unroll
            for (int q = 0; q < 2; ++q) {
                const int item = tid + q * 256;
                const int b  = item >> 3;
                const int jc = item & 7;
                const int m  = b >> 4, br = b & 15;
                float rr = 0.f, zz = 0.f, nx = 0.f, nh = 0.f;
#pragma unroll
                for (int ww = 0; ww < 4; ++ww) {
                    rr += lds[ww][m][0][br * 16 + jc];
                    zz += lds[ww][m][0][br * 16 + 8 + jc];
                    nx += lds[ww][m][1][br * 16 + jc];
                    nh += lds[ww][m][2][br * 16 + jc];
                }
                const int j = j0 + jc;
                const float r = sigm_(rr + bi[j] + bh_[j]);
                const float z = sigm_(zz + bi[HID + j] + bh_[HID + j]);
                const float n = tanh_((nx + bi[2 * HID + j]) + r * (nh + bh_[2 * HID + j]));
                const long pofs = ((long)(layer * 2 + rp) * NB + b) * HID + j;
                const long nofs = ((long)(layer * 2 + wp) * NB + b) * HID + j;
                const float hp = hf[pofs];
                const float hnew = (1.f - z) * hp + z * n;
                hf[nofs] = hnew;
                hb[nofs] = f2bf(hnew);
                if (layer) out[((long)b * SEQ + st) * HID + j] = hnew;
            }
            __syncthreads();   // protect lds reuse before next interval's writes
        }
        grid_barrier(bar, bid);
    }
}

__global__ __launch_bounds__(256) void cvt_bf16(const float* __restrict__ src,
                                                unsigned short* __restrict__ dst, int n4) {
    int i = blockIdx.x * 256 + threadIdx.x;
    if (i >= n4) return;
    float4 f = *(const float4*)(src + 4L * i);
    unsigned long long u =  (unsigned long long)f2bf(f.x)
                         | ((unsigned long long)f2bf(f.y) << 16)
                         | ((unsigned long long)f2bf(f.z) << 32)
                         | ((unsigned long long)f2bf(f.w) << 48);
    *(unsigned long long*)(dst + 4L * i) = u;
}

__global__ __launch_bounds__(256) void init_h(const float* __restrict__ h0,
                                              float* __restrict__ hf,
                                              unsigned short* __restrict__ hb) {
    int i = blockIdx.x * 256 + threadIdx.x;          // 2*64*1024 threads
    int layer = i >> 16, idx = i & 65535;
    float v = h0[i];
    hf[(long)(layer * 2 + 0) * 65536 + idx] = v;     // parity 0
    hb[(long)(layer * 2 + 0) * 65536 + idx] = f2bf(v);
}

extern "C" void kernel_launch(void* const* d_in, const int* in_sizes, int n_in,
                              void* d_out, int out_size, void* d_ws, size_t ws_size,
                              hipStream_t stream) {
    const float* x    = (const float*)d_in[0];
    const float* h0   = (const float*)d_in[1];
    const float* Wih0 = (const float*)d_in[2];
    const float* Whh0 = (const float*)d_in[3];
    const float* bih0 = (const float*)d_in[4];
    const float* bhh0 = (const float*)d_in[5];
    const float* Wih1 = (const float*)d_in[6];
    const float* Whh1 = (const float*)d_in[7];
    const float* bih1 = (const float*)d_in[8];
    const float* bhh1 = (const float*)d_in[9];

    float* out   = (float*)d_out;                    // [64][512][1024]
    float* hnout = out + (long)NB * SEQ * HID;       // [2][64][1024]

    // ws layout (~22.6 MiB + barrier):
    unsigned short* W0i = (unsigned short*)d_ws;             // [3072][512]
    unsigned short* W0h = W0i + 3072L * 512;                 // [3072][1024]
    unsigned short* W1i = W0h + 3072L * 1024;
    unsigned short* W1h = W1i + 3072L * 1024;
    float*          hf  = (float*)(W1h + 3072L * 1024);      // [2][2][64][1024] f32
    unsigned short* hb  = (unsigned short*)(hf + 4L * 65536);
    unsigned*       bar = (unsigned*)(hb + 4L * 65536);      // barrier lines

    // barrier counters MUST be zero each call (ws is poisoned before timing)
    hipMemsetAsync(bar, 0, 1024, stream);

    cvt_bf16<<<(3072 * 512 / 4  + 255) / 256, 256, 0, stream>>>(Wih0, W0i, 3072 * 512 / 4);
    cvt_bf16<<<(3072 * 1024 / 4 + 255) / 256, 256, 0, stream>>>(Whh0, W0h, 3072 * 1024 / 4);
    cvt_bf16<<<(3072 * 1024 / 4 + 255) / 256, 256, 0, stream>>>(Whh1 ? Wih1 : Wih1, W1i, 3072 * 1024 / 4);
    cvt_bf16<<<(3072 * 1024 / 4 + 255) / 256, 256, 0, stream>>>(Whh1, W1h, 3072 * 1024 / 4);
    init_h<<<512, 256, 0, stream>>>(h0, hf, hb);

    // Plain launch: grid 256 = #CUs, 1-block/CU resources -> all co-resident,
    // so the device-scope tree barrier is valid without the cooperative API
    // (whose launch silently failed in R3).
    gru_persist<<<256, 256, 0, stream>>>(x, W0i, W0h, W1i, W1h,
                                         bih0, bhh0, bih1, bhh1,
                                         hf, hb, out, bar);

    // both layers' t=511 state lands in parity 0
    hipMemcpyAsync(hnout,         hf,              65536 * sizeof(float),
                   hipMemcpyDeviceToDevice, stream);
    hipMemcpyAsync(hnout + 65536, hf + 2L * 65536, 65536 * sizeof(float),
                   hipMemcpyDeviceToDevice, stream);
}

// Round 5
// 17924.825 us; speedup vs baseline: 2.7718x; 2.7718x over previous
//
#include <hip/hip_runtime.h>
#include <math.h>

#define HID  1024
#define SEQ  512
#define NB   64
#define DIN0 512

using short8 = __attribute__((ext_vector_type(8))) short;
using f32x4  = __attribute__((ext_vector_type(4))) float;

__device__ __forceinline__ unsigned short f2bf(float f) {
    unsigned int u = __float_as_uint(f);
    u += 0x7fffu + ((u >> 16) & 1u);          // round-to-nearest-even
    return (unsigned short)(u >> 16);
}
__device__ __forceinline__ float sigm_(float x) { return 1.0f / (1.0f + __expf(-x)); }
__device__ __forceinline__ float tanh_(float x) {
    float ax = fabsf(x);
    float e = __expf(-2.0f * ax);
    float t = (1.0f - e) / (1.0f + e);
    return copysignf(t, x);
}
__device__ __forceinline__ short8 pack8(const float* p) {
    float4 f0 = *(const float4*)p;
    float4 f1 = *(const float4*)(p + 4);
    short8 pk;
    pk[0] = (short)f2bf(f0.x); pk[1] = (short)f2bf(f0.y);
    pk[2] = (short)f2bf(f0.z); pk[3] = (short)f2bf(f0.w);
    pk[4] = (short)f2bf(f1.x); pk[5] = (short)f2bf(f1.y);
    pk[6] = (short)f2bf(f1.z); pk[7] = (short)f2bf(f1.w);
    return pk;
}

// Coherent (device-visible) access to the shared h-state: write-through stores
// and L1/L2-bypass loads via sc0 sc1. No cache flush/invalidate fences needed.
__device__ __forceinline__ void cstore_u32(unsigned short* p, unsigned v) {
    asm volatile("global_store_dword %0, %1, off sc0 sc1" :: "v"(p), "v"(v) : "memory");
}
__device__ __forceinline__ void cload_4(short8 a[4], const unsigned short* base, int c) {
    const unsigned short* p0 = base + (long)(c)      * HID;
    const unsigned short* p1 = base + (long)(16 + c) * HID;
    const unsigned short* p2 = base + (long)(32 + c) * HID;
    const unsigned short* p3 = base + (long)(48 + c) * HID;
    asm volatile(
        "global_load_dwordx4 %0, %4, off sc0 sc1\n\t"
        "global_load_dwordx4 %1, %5, off sc0 sc1\n\t"
        "global_load_dwordx4 %2, %6, off sc0 sc1\n\t"
        "global_load_dwordx4 %3, %7, off sc0 sc1\n\t"
        "s_waitcnt vmcnt(0)"
        : "=&v"(a[0]), "=&v"(a[1]), "=&v"(a[2]), "=&v"(a[3])
        : "v"(p0), "v"(p1), "v"(p2), "v"(p3)
        : "memory");
}

// Tree grid barrier, NO threadfence: shared data is write-through + bypass-read,
// so visibility is per-access; we only drain our own VMEM queue before arriving.
// Requires all 256 blocks co-resident (grid = #CUs, 1-block/CU resources).
__device__ __forceinline__ void grid_barrier(unsigned* bar, int bid) {
    asm volatile("s_waitcnt vmcnt(0)" ::: "memory");   // our coherent stores are at L3
    __syncthreads();
    if (threadIdx.x == 0) {
        unsigned* gen  = bar;
        unsigned* root = bar + 16;
        unsigned* sub  = bar + 32 + (bid & 7) * 16;
        unsigned g = __hip_atomic_load(gen, __ATOMIC_RELAXED, __HIP_MEMORY_SCOPE_AGENT);
        if (__hip_atomic_fetch_add(sub, 1u, __ATOMIC_ACQ_REL, __HIP_MEMORY_SCOPE_AGENT) == 31u) {
            __hip_atomic_store(sub, 0u, __ATOMIC_RELAXED, __HIP_MEMORY_SCOPE_AGENT);
            if (__hip_atomic_fetch_add(root, 1u, __ATOMIC_ACQ_REL, __HIP_MEMORY_SCOPE_AGENT) == 7u) {
                __hip_atomic_store(root, 0u, __ATOMIC_RELAXED, __HIP_MEMORY_SCOPE_AGENT);
                __hip_atomic_fetch_add(gen, 1u, __ATOMIC_RELEASE, __HIP_MEMORY_SCOPE_AGENT);
            }
        }
        while (__hip_atomic_load(gen, __ATOMIC_ACQUIRE, __HIP_MEMORY_SCOPE_AGENT) == g)
            __builtin_amdgcn_s_sleep(2);
    }
    __syncthreads();
}

// Per-layer persistent loop, LAYER compile-time so weight frags are fully
// register-resident (nkst static) and x/h load paths are specialized.
template<int LAYER>
__device__ __forceinline__ void gru_loop(
    const float* __restrict__ x,
    const unsigned short* __restrict__ Wi, const unsigned short* __restrict__ Wh,
    const float* __restrict__ bi, const float* __restrict__ bh_,
    float* __restrict__ hf, unsigned short* __restrict__ hb,
    float* __restrict__ out, unsigned* __restrict__ bar,
    int bid, float (*lds)[4][3][272])
{
    constexpr int Din = LAYER ? HID : DIN0;
    constexpr int Kq  = (Din + HID) / 4;     // 512 or 384
    constexpr int NK  = Kq / 32;             // 16 or 12

    const int j0  = (bid & 127) << 3;
    const int tid = threadIdx.x;
    const int l   = tid & 63;
    const int w   = tid >> 6;     // wave id = K-quarter
    const int c   = l & 15;       // frag col / A row
    const int kg  = l >> 4;       // k subgroup
    const int kq0 = w * Kq;

    // ---- one-time: weight B-frags into registers ----
    // n-tile0 packs [r | z] (col<8 -> r row, col>=8 -> z row); n-tile1 = n gate.
    const int row0 = ((c < 8) ? 0 : HID) + j0 + (c & 7);
    const int row1 = 2 * HID + j0 + (c & 7);
    short8 Bw0[NK], Bw1[NK];
#pragma unroll
    for (int s = 0; s < NK; ++s) {
        const int k0 = kq0 + s * 32 + kg * 8;
        const unsigned short *p0, *p1;
        if (k0 < Din) { p0 = Wi + (long)row0 * Din + k0;         p1 = Wi + (long)row1 * Din + k0; }
        else          { p0 = Wh + (long)row0 * HID + (k0 - Din); p1 = Wh + (long)row1 * HID + (k0 - Din); }
        Bw0[s] = *(const short8*)p0;
        Bw1[s] = *(const short8*)p1;
    }

    // ---- combine-phase loop-invariants (thread -> (b, j0+jc0..jc0+1)) ----
    const int cb  = tid >> 2;                // batch 0..63
    const int jc0 = (tid & 3) * 2;           // 0,2,4,6
    const int cm  = cb >> 4, cbr = cb & 15;
    const int j   = j0 + jc0;
    const float bir = bi[j],           bir1 = bi[j + 1];
    const float biz = bi[HID + j],     biz1 = bi[HID + j + 1];
    const float bin = bi[2*HID + j],   bin1 = bi[2*HID + j + 1];
    const float bhr = bh_[j],          bhr1 = bh_[j + 1];
    const float bhz = bh_[HID + j],    bhz1 = bh_[HID + j + 1];
    const float bhn = bh_[2*HID + j],  bhn1 = bh_[2*HID + j + 1];

    for (int i = 0; i <= SEQ; ++i) {
        const int st = LAYER ? (i - 1) : i;
        if (st >= 0 && st < SEQ) {
            const int rp = st & 1, wp = rp ^ 1;
            const unsigned short* Alo = hb + (long)(0 * 2 + wp) * NB * HID;      // L1: out0(st)
            const unsigned short* Ahi = hb + (long)(LAYER * 2 + rp) * NB * HID;  // own h(st-1)

            f32x4 acc_rz[4], acc_nx[4], acc_nh[4];
#pragma unroll
            for (int m = 0; m < 4; ++m) {
                acc_rz[m] = (f32x4){0.f, 0.f, 0.f, 0.f};
                acc_nx[m] = (f32x4){0.f, 0.f, 0.f, 0.f};
                acc_nh[m] = (f32x4){0.f, 0.f, 0.f, 0.f};
            }

#pragma unroll
            for (int s = 0; s < NK; ++s) {
                const int kk = kq0 + s * 32 + kg * 8;
                const bool lo = (kq0 + s * 32) < Din;    // wave-uniform
                short8 a[4];
                if (LAYER == 0) {
                    if (lo) {
#pragma unroll
                        for (int m = 0; m < 4; ++m)
                            a[m] = pack8(x + ((long)(m * 16 + c) * SEQ + st) * DIN0 + kk);
                    } else {
                        cload_4(a, Ahi + (kk - DIN0), c);
                    }
                } else {
                    cload_4(a, lo ? (Alo + kk) : (Ahi + (kk - HID)), c);
                }
#pragma unroll
                for (int m = 0; m < 4; ++m)
                    acc_rz[m] = __builtin_amdgcn_mfma_f32_16x16x32_bf16(a[m], Bw0[s], acc_rz[m], 0, 0, 0);
                if (lo) {
#pragma unroll
                    for (int m = 0; m < 4; ++m)
                        acc_nx[m] = __builtin_amdgcn_mfma_f32_16x16x32_bf16(a[m], Bw1[s], acc_nx[m], 0, 0, 0);
                } else {
#pragma unroll
                    for (int m = 0; m < 4; ++m)
                        acc_nh[m] = __builtin_amdgcn_mfma_f32_16x16x32_bf16(a[m], Bw1[s], acc_nh[m], 0, 0, 0);
                }
            }

            // ---- K-quarter partials -> LDS (padded rows: stride 17) ----
#pragma unroll
            for (int m = 0; m < 4; ++m)
#pragma unroll
                for (int v = 0; v < 4; ++v) {
                    const int rc = (kg * 4 + v) * 17 + c;   // C/D: row=(l>>4)*4+v, col=l&15
                    lds[w][m][0][rc] = acc_rz[m][v];
                    lds[w][m][1][rc] = acc_nx[m][v];
                    lds[w][m][2][rc] = acc_nh[m][v];
                }
            __syncthreads();

            // ---- combine + pointwise: 2 consecutive-j items per thread ----
            float rr0 = 0.f, zz0 = 0.f, nx0 = 0.f, nh0 = 0.f;
            float rr1 = 0.f, zz1 = 0.f, nx1 = 0.f, nh1 = 0.f;
#pragma unroll
            for (int ww = 0; ww < 4; ++ww) {
                rr0 += lds[ww][cm][0][cbr * 17 + jc0];
                rr1 += lds[ww][cm][0][cbr * 17 + jc0 + 1];
                zz0 += lds[ww][cm][0][cbr * 17 + 8 + jc0];
                zz1 += lds[ww][cm][0][cbr * 17 + 8 + jc0 + 1];
                nx0 += lds[ww][cm][1][cbr * 17 + jc0];
                nx1 += lds[ww][cm][1][cbr * 17 + jc0 + 1];
                nh0 += lds[ww][cm][2][cbr * 17 + jc0];
                nh1 += lds[ww][cm][2][cbr * 17 + jc0 + 1];
            }
            const float r0 = sigm_(rr0 + bir + bhr);
            const float r1 = sigm_(rr1 + bir1 + bhr1);
            const float z0 = sigm_(zz0 + biz + bhz);
            const float z1 = sigm_(zz1 + biz1 + bhz1);
            const float n0 = tanh_((nx0 + bin)  + r0 * (nh0 + bhn));
            const float n1 = tanh_((nx1 + bin1) + r1 * (nh1 + bhn1));

            const long pofs = ((long)(LAYER * 2 + rp) * NB + cb) * HID + j;
            const long nofs = ((long)(LAYER * 2 + wp) * NB + cb) * HID + j;
            const float2 hp = *(const float2*)(hf + pofs);      // block-private, cached
            const float h0n = (1.f - z0) * hp.x + z0 * n0;
            const float h1n = (1.f - z1) * hp.y + z1 * n1;
            *(float2*)(hf + nofs) = make_float2(h0n, h1n);
            cstore_u32(hb + nofs, (unsigned)f2bf(h0n) | ((unsigned)f2bf(h1n) << 16));
            if (LAYER) *(float2*)(out + ((long)cb * SEQ + st) * HID + j) = make_float2(h0n, h1n);
        }
        grid_barrier(bar, bid);
    }
}

__global__ __launch_bounds__(256, 1) void gru_persist(
    const float* __restrict__ x,
    const unsigned short* __restrict__ W0i, const unsigned short* __restrict__ W0h,
    const unsigned short* __restrict__ W1i, const unsigned short* __restrict__ W1h,
    const float* __restrict__ bi0, const float* __restrict__ bh0,
    const float* __restrict__ bi1, const float* __restrict__ bh1,
    float* __restrict__ hf, unsigned short* __restrict__ hb,
    float* __restrict__ out, unsigned* __restrict__ bar)
{
    __shared__ float lds[4][4][3][272];   // [wave][m][rz|nx|nh][16 rows x 17]
    const int bid = blockIdx.x;
    if (bid < 128) gru_loop<0>(x, W0i, W0h, bi0, bh0, hf, hb, out, bar, bid, lds);
    else           gru_loop<1>(x, W1i, W1h, bi1, bh1, hf, hb, out, bar, bid, lds);
}

__global__ __launch_bounds__(256) void cvt_bf16(const float* __restrict__ src,
                                                unsigned short* __restrict__ dst, int n4) {
    int i = blockIdx.x * 256 + threadIdx.x;
    if (i >= n4) return;
    float4 f = *(const float4*)(src + 4L * i);
    unsigned long long u =  (unsigned long long)f2bf(f.x)
                         | ((unsigned long long)f2bf(f.y) << 16)
                         | ((unsigned long long)f2bf(f.z) << 32)
                         | ((unsigned long long)f2bf(f.w) << 48);
    *(unsigned long long*)(dst + 4L * i) = u;
}

__global__ __launch_bounds__(256) void init_h(const float* __restrict__ h0,
                                              float* __restrict__ hf,
                                              unsigned short* __restrict__ hb) {
    int i = blockIdx.x * 256 + threadIdx.x;          // 2*64*1024 threads
    int layer = i >> 16, idx = i & 65535;
    float v = h0[i];
    hf[(long)(layer * 2 + 0) * 65536 + idx] = v;     // parity 0
    hb[(long)(layer * 2 + 0) * 65536 + idx] = f2bf(v);
}

extern "C" void kernel_launch(void* const* d_in, const int* in_sizes, int n_in,
                              void* d_out, int out_size, void* d_ws, size_t ws_size,
                              hipStream_t stream) {
    const float* x    = (const float*)d_in[0];
    const float* h0   = (const float*)d_in[1];
    const float* Wih0 = (const float*)d_in[2];
    const float* Whh0 = (const float*)d_in[3];
    const float* bih0 = (const float*)d_in[4];
    const float* bhh0 = (const float*)d_in[5];
    const float* Wih1 = (const float*)d_in[6];
    const float* Whh1 = (const float*)d_in[7];
    const float* bih1 = (const float*)d_in[8];
    const float* bhh1 = (const float*)d_in[9];

    float* out   = (float*)d_out;                    // [64][512][1024]
    float* hnout = out + (long)NB * SEQ * HID;       // [2][64][1024]

    // ws layout (~23.3 MiB):
    unsigned short* W0i = (unsigned short*)d_ws;             // [3072][512]
    unsigned short* W0h = W0i + 3072L * 512;                 // [3072][1024]
    unsigned short* W1i = W0h + 3072L * 1024;
    unsigned short* W1h = W1i + 3072L * 1024;
    float*          hf  = (float*)(W1h + 3072L * 1024);      // [2][2][64][1024] f32
    unsigned short* hb  = (unsigned short*)(hf + 4L * 65536);
    unsigned*       bar = (unsigned*)(hb + 4L * 65536);      // barrier lines

    // barrier counters MUST be zero each call (ws is poisoned before timing)
    hipMemsetAsync(bar, 0, 1024, stream);

    cvt_bf16<<<(3072 * 512 / 4  + 255) / 256, 256, 0, stream>>>(Wih0, W0i, 3072 * 512 / 4);
    cvt_bf16<<<(3072 * 1024 / 4 + 255) / 256, 256, 0, stream>>>(Whh0, W0h, 3072 * 1024 / 4);
    cvt_bf16<<<(3072 * 1024 / 4 + 255) / 256, 256, 0, stream>>>(Wih1, W1i, 3072 * 1024 / 4);
    cvt_bf16<<<(3072 * 1024 / 4 + 255) / 256, 256, 0, stream>>>(Whh1, W1h, 3072 * 1024 / 4);
    init_h<<<512, 256, 0, stream>>>(h0, hf, hb);

    gru_persist<<<256, 256, 0, stream>>>(x, W0i, W0h, W1i, W1h,
                                         bih0, bhh0, bih1, bhh1,
                                         hf, hb, out, bar);

    // both layers' t=511 state lands in parity 0
    hipMemcpyAsync(hnout,         hf,              65536 * sizeof(float),
                   hipMemcpyDeviceToDevice, stream);
    hipMemcpyAsync(hnout + 65536, hf + 2L * 65536, 65536 * sizeof(float),
                   hipMemcpyDeviceToDevice, stream);
}

// Round 6
// 9811.062 us; speedup vs baseline: 5.0640x; 1.8270x over previous
//
#include <hip/hip_runtime.h>
#include <math.h>

#define HID  1024
#define SEQ  512
#define NB   64
#define DIN0 512

using short8 = __attribute__((ext_vector_type(8))) short;
using f32x4  = __attribute__((ext_vector_type(4))) float;

__device__ __forceinline__ unsigned short f2bf(float f) {
    unsigned int u = __float_as_uint(f);
    u += 0x7fffu + ((u >> 16) & 1u);          // round-to-nearest-even
    return (unsigned short)(u >> 16);
}
__device__ __forceinline__ float sigm_(float x) { return 1.0f / (1.0f + __expf(-x)); }
__device__ __forceinline__ float tanh_(float x) {
    float ax = fabsf(x);
    float e = __expf(-2.0f * ax);
    float t = (1.0f - e) / (1.0f + e);
    return copysignf(t, x);
}
__device__ __forceinline__ short8 pack8(const float* p) {
    float4 f0 = *(const float4*)p;
    float4 f1 = *(const float4*)(p + 4);
    short8 pk;
    pk[0] = (short)f2bf(f0.x); pk[1] = (short)f2bf(f0.y);
    pk[2] = (short)f2bf(f0.z); pk[3] = (short)f2bf(f0.w);
    pk[4] = (short)f2bf(f1.x); pk[5] = (short)f2bf(f1.y);
    pk[6] = (short)f2bf(f1.z); pk[7] = (short)f2bf(f1.w);
    return pk;
}

// Persistent fused 2-layer GRU. 256 blocks x 512 thr (8 waves, 2/SIMD), one
// block per CU. Coherence model: plain cached loads/stores everywhere; ONE
// release fence (wbl2) + ONE acquire fence (inv) per block per interval,
// executed by wave 0 only. Weights live in VGPRs (per-wave K-eighth).
template<int LAYER>
__device__ __forceinline__ void gru_loop(
    const float* __restrict__ x,
    const unsigned short* __restrict__ Wi, const unsigned short* __restrict__ Wh,
    const float* __restrict__ bi, const float* __restrict__ bh_,
    float* __restrict__ hf, unsigned short* __restrict__ hb,
    float* __restrict__ out, unsigned* __restrict__ bar,
    int bid, float (*lds)[4][3][272])
{
    constexpr int Din = LAYER ? HID : DIN0;
    constexpr int K   = Din + HID;
    constexpr int Kq  = K / 8;               // per-wave K range: 192 or 256
    constexpr int NK  = Kq / 32;             // 6 or 8 K-steps per wave

    const int j0  = (bid & 127) << 3;
    const int tid = threadIdx.x;
    const int l   = tid & 63;
    const int w   = tid >> 6;                // wave id 0..7 = K-eighth
    const int c   = l & 15;                  // frag col / A row
    const int kg  = l >> 4;                  // k subgroup
    const int kq0 = w * Kq;

    // ---- one-time: weight B-frags into registers (48 or 64 VGPRs) ----
    // tile0 packs [r | z] (col<8 -> r row, col>=8 -> z row); tile1 = n gate.
    const int row0 = ((c < 8) ? 0 : HID) + j0 + (c & 7);
    const int row1 = 2 * HID + j0 + (c & 7);
    short8 Bw0[NK], Bw1[NK];
#pragma unroll
    for (int s = 0; s < NK; ++s) {
        const int k0 = kq0 + s * 32 + kg * 8;
        const unsigned short *p0, *p1;
        if (k0 < Din) { p0 = Wi + (long)row0 * Din + k0;         p1 = Wi + (long)row1 * Din + k0; }
        else          { p0 = Wh + (long)row0 * HID + (k0 - Din); p1 = Wh + (long)row1 * HID + (k0 - Din); }
        Bw0[s] = *(const short8*)p0;
        Bw1[s] = *(const short8*)p1;
    }

    // ---- combine-phase loop invariants: thread -> (batch cb, col j0+jc) ----
    const int cb  = tid >> 3;                // 0..63
    const int jc  = tid & 7;
    const int cm  = cb >> 4, cbr = cb & 15;
    const int j   = j0 + jc;
    const float bir = bi[j], biz = bi[HID + j], bin = bi[2 * HID + j];
    const float bhr = bh_[j], bhz = bh_[HID + j], bhn = bh_[2 * HID + j];

    for (int i = 0; i <= SEQ; ++i) {
        const int st = LAYER ? (i - 1) : i;
        if (st >= 0 && st < SEQ) {
            const int rp = st & 1, wp = rp ^ 1;
            const unsigned short* Alo = hb + (long)(0 * 2 + wp) * NB * HID;      // L1: out0(st)
            const unsigned short* Ahi = hb + (long)(LAYER * 2 + rp) * NB * HID;  // own h(st-1)

            f32x4 acc_rz[4], acc_nx[4], acc_nh[4];
#pragma unroll
            for (int m = 0; m < 4; ++m) {
                acc_rz[m] = (f32x4){0.f, 0.f, 0.f, 0.f};
                acc_nx[m] = (f32x4){0.f, 0.f, 0.f, 0.f};
                acc_nh[m] = (f32x4){0.f, 0.f, 0.f, 0.f};
            }

#pragma unroll
            for (int s = 0; s < NK; ++s) {
                const int kk = kq0 + s * 32 + kg * 8;
                const bool lo = (kq0 + s * 32) < Din;    // wave-uniform
                short8 a[4];
                if (LAYER == 0) {
                    if (lo) {
#pragma unroll
                        for (int m = 0; m < 4; ++m)
                            a[m] = pack8(x + ((long)(m * 16 + c) * SEQ + st) * DIN0 + kk);
                    } else {
#pragma unroll
                        for (int m = 0; m < 4; ++m)
                            a[m] = *(const short8*)(Ahi + (long)(m * 16 + c) * HID + (kk - DIN0));
                    }
                } else {
                    const unsigned short* base = lo ? (Alo + kk) : (Ahi + (kk - HID));
#pragma unroll
                    for (int m = 0; m < 4; ++m)
                        a[m] = *(const short8*)(base + (long)(m * 16 + c) * HID);
                }
#pragma unroll
                for (int m = 0; m < 4; ++m)
                    acc_rz[m] = __builtin_amdgcn_mfma_f32_16x16x32_bf16(a[m], Bw0[s], acc_rz[m], 0, 0, 0);
                if (lo) {
#pragma unroll
                    for (int m = 0; m < 4; ++m)
                        acc_nx[m] = __builtin_amdgcn_mfma_f32_16x16x32_bf16(a[m], Bw1[s], acc_nx[m], 0, 0, 0);
                } else {
#pragma unroll
                    for (int m = 0; m < 4; ++m)
                        acc_nh[m] = __builtin_amdgcn_mfma_f32_16x16x32_bf16(a[m], Bw1[s], acc_nh[m], 0, 0, 0);
                }
            }

            // ---- two-phase cross-wave reduction in LDS (52 KB) ----
            if (w >= 4) {
#pragma unroll
                for (int m = 0; m < 4; ++m)
#pragma unroll
                    for (int v = 0; v < 4; ++v) {
                        const int rc = (kg * 4 + v) * 17 + c;  // C/D: row=(l>>4)*4+v, col=l&15
                        lds[w - 4][m][0][rc] = acc_rz[m][v];
                        lds[w - 4][m][1][rc] = acc_nx[m][v];
                        lds[w - 4][m][2][rc] = acc_nh[m][v];
                    }
            }
            __syncthreads();
            if (w < 4) {
#pragma unroll
                for (int m = 0; m < 4; ++m)
#pragma unroll
                    for (int v = 0; v < 4; ++v) {
                        const int rc = (kg * 4 + v) * 17 + c;
                        lds[w][m][0][rc] += acc_rz[m][v];
                        lds[w][m][1][rc] += acc_nx[m][v];
                        lds[w][m][2][rc] += acc_nh[m][v];
                    }
            }
            __syncthreads();

            // ---- combine 4 pairwise sums + pointwise: 1 item/thread ----
            float rr = 0.f, zz = 0.f, nx = 0.f, nh = 0.f;
#pragma unroll
            for (int ww = 0; ww < 4; ++ww) {
                rr += lds[ww][cm][0][cbr * 17 + jc];
                zz += lds[ww][cm][0][cbr * 17 + 8 + jc];
                nx += lds[ww][cm][1][cbr * 17 + jc];
                nh += lds[ww][cm][2][cbr * 17 + jc];
            }
            const float r = sigm_(rr + bir + bhr);
            const float z = sigm_(zz + biz + bhz);
            const float n = tanh_((nx + bin) + r * (nh + bhn));
            const long pofs = ((long)(LAYER * 2 + rp) * NB + cb) * HID + j;
            const long nofs = ((long)(LAYER * 2 + wp) * NB + cb) * HID + j;
            const float hp = hf[pofs];                     // block-private
            const float hnew = (1.f - z) * hp + z * n;
            hf[nofs] = hnew;
            hb[nofs] = f2bf(hnew);
            if (LAYER) out[((long)cb * SEQ + st) * HID + j] = hnew;
            __syncthreads();   // lds safe for next interval's phase-1 writes
        }

        // ---- grid barrier: 1 wbl2 + 1 inv per block per interval ----
        asm volatile("s_waitcnt vmcnt(0)" ::: "memory");   // drain this wave's stores to L2
        __syncthreads();
        if (tid < 64) {                                    // wave 0 only
            __builtin_amdgcn_fence(__ATOMIC_RELEASE, "agent");   // L2 writeback
            if (tid == 0) {
                unsigned* gen  = bar;
                unsigned* root = bar + 16;
                unsigned* sub  = bar + 32 + (bid & 7) * 16;
                unsigned g = __hip_atomic_load(gen, __ATOMIC_RELAXED, __HIP_MEMORY_SCOPE_AGENT);
                if (__hip_atomic_fetch_add(sub, 1u, __ATOMIC_RELAXED, __HIP_MEMORY_SCOPE_AGENT) == 31u) {
                    __hip_atomic_store(sub, 0u, __ATOMIC_RELAXED, __HIP_MEMORY_SCOPE_AGENT);
                    asm volatile("s_waitcnt vmcnt(0)" ::: "memory");  // reset lands before root add
                    if (__hip_atomic_fetch_add(root, 1u, __ATOMIC_RELAXED, __HIP_MEMORY_SCOPE_AGENT) == 7u) {
                        __hip_atomic_store(root, 0u, __ATOMIC_RELAXED, __HIP_MEMORY_SCOPE_AGENT);
                        asm volatile("s_waitcnt vmcnt(0)" ::: "memory");
                        __hip_atomic_fetch_add(gen, 1u, __ATOMIC_RELAXED, __HIP_MEMORY_SCOPE_AGENT);
                    }
                }
                while (__hip_atomic_load(gen, __ATOMIC_RELAXED, __HIP_MEMORY_SCOPE_AGENT) == g)
                    __builtin_amdgcn_s_sleep(8);
            }
            __builtin_amdgcn_fence(__ATOMIC_ACQUIRE, "agent");   // L1+L2 invalidate
        }
        __syncthreads();
    }
}

__global__ __launch_bounds__(512, 2) void gru_persist(
    const float* __restrict__ x,
    const unsigned short* __restrict__ W0i, const unsigned short* __restrict__ W0h,
    const unsigned short* __restrict__ W1i, const unsigned short* __restrict__ W1h,
    const float* __restrict__ bi0, const float* __restrict__ bh0,
    const float* __restrict__ bi1, const float* __restrict__ bh1,
    float* __restrict__ hf, unsigned short* __restrict__ hb,
    float* __restrict__ out, unsigned* __restrict__ bar)
{
    __shared__ float lds[4][4][3][272];   // [wavepair][m][rz|nx|nh][16 rows x 17]
    const int bid = blockIdx.x;
    if (bid < 128) gru_loop<0>(x, W0i, W0h, bi0, bh0, hf, hb, out, bar, bid, lds);
    else           gru_loop<1>(x, W1i, W1h, bi1, bh1, hf, hb, out, bar, bid, lds);
}

__global__ __launch_bounds__(256) void cvt_bf16(const float* __restrict__ src,
                                                unsigned short* __restrict__ dst, int n4) {
    int i = blockIdx.x * 256 + threadIdx.x;
    if (i >= n4) return;
    float4 f = *(const float4*)(src + 4L * i);
    unsigned long long u =  (unsigned long long)f2bf(f.x)
                         | ((unsigned long long)f2bf(f.y) << 16)
                         | ((unsigned long long)f2bf(f.z) << 32)
                         | ((unsigned long long)f2bf(f.w) << 48);
    *(unsigned long long*)(dst + 4L * i) = u;
}

__global__ __launch_bounds__(256) void init_h(const float* __restrict__ h0,
                                              float* __restrict__ hf,
                                              unsigned short* __restrict__ hb) {
    int i = blockIdx.x * 256 + threadIdx.x;          // 2*64*1024 threads
    int layer = i >> 16, idx = i & 65535;
    float v = h0[i];
    hf[(long)(layer * 2 + 0) * 65536 + idx] = v;     // parity 0
    hb[(long)(layer * 2 + 0) * 65536 + idx] = f2bf(v);
}

extern "C" void kernel_launch(void* const* d_in, const int* in_sizes, int n_in,
                              void* d_out, int out_size, void* d_ws, size_t ws_size,
                              hipStream_t stream) {
    const float* x    = (const float*)d_in[0];
    const float* h0   = (const float*)d_in[1];
    const float* Wih0 = (const float*)d_in[2];
    const float* Whh0 = (const float*)d_in[3];
    const float* bih0 = (const float*)d_in[4];
    const float* bhh0 = (const float*)d_in[5];
    const float* Wih1 = (const float*)d_in[6];
    const float* Whh1 = (const float*)d_in[7];
    const float* bih1 = (const float*)d_in[8];
    const float* bhh1 = (const float*)d_in[9];

    float* out   = (float*)d_out;                    // [64][512][1024]
    float* hnout = out + (long)NB * SEQ * HID;       // [2][64][1024]

    // ws layout (~23.3 MiB):
    unsigned short* W0i = (unsigned short*)d_ws;             // [3072][512]
    unsigned short* W0h = W0i + 3072L * 512;                 // [3072][1024]
    unsigned short* W1i = W0h + 3072L * 1024;
    unsigned short* W1h = W1i + 3072L * 1024;
    float*          hf  = (float*)(W1h + 3072L * 1024);      // [2][2][64][1024] f32
    unsigned short* hb  = (unsigned short*)(hf + 4L * 65536);
    unsigned*       bar = (unsigned*)(hb + 4L * 65536);      // barrier lines

    // barrier counters MUST be zero each call (ws is poisoned before timing)
    hipMemsetAsync(bar, 0, 1024, stream);

    cvt_bf16<<<(3072 * 512 / 4  + 255) / 256, 256, 0, stream>>>(Wih0, W0i, 3072 * 512 / 4);
    cvt_bf16<<<(3072 * 1024 / 4 + 255) / 256, 256, 0, stream>>>(Whh0, W0h, 3072 * 1024 / 4);
    cvt_bf16<<<(3072 * 1024 / 4 + 255) / 256, 256, 0, stream>>>(Wih1, W1i, 3072 * 1024 / 4);
    cvt_bf16<<<(3072 * 1024 / 4 + 255) / 256, 256, 0, stream>>>(Whh1, W1h, 3072 * 1024 / 4);
    init_h<<<512, 256, 0, stream>>>(h0, hf, hb);

    gru_persist<<<256, 512, 0, stream>>>(x, W0i, W0h, W1i, W1h,
                                         bih0, bhh0, bih1, bhh1,
                                         hf, hb, out, bar);

    // both layers' t=511 state lands in parity 0
    hipMemcpyAsync(hnout,         hf,              65536 * sizeof(float),
                   hipMemcpyDeviceToDevice, stream);
    hipMemcpyAsync(hnout + 65536, hf + 2L * 65536, 65536 * sizeof(float),
                   hipMemcpyDeviceToDevice, stream);
}

// Round 7
// 6416.266 us; speedup vs baseline: 7.7433x; 1.5291x over previous
//
#include <hip/hip_runtime.h>
#include <math.h>

#define HID  1024
#define SEQ  512
#define NB   64
#define DIN0 512

using short8 = __attribute__((ext_vector_type(8))) short;
using f32x4  = __attribute__((ext_vector_type(4))) float;

__device__ __forceinline__ unsigned short f2bf(float f) {
    unsigned int u = __float_as_uint(f);
    u += 0x7fffu + ((u >> 16) & 1u);          // round-to-nearest-even
    return (unsigned short)(u >> 16);
}
__device__ __forceinline__ float sigm_(float x) { return 1.0f / (1.0f + __expf(-x)); }
__device__ __forceinline__ float tanh_(float x) {
    float ax = fabsf(x);
    float e = __expf(-2.0f * ax);
    float t = (1.0f - e) / (1.0f + e);
    return copysignf(t, x);
}

// ---- no-wait load issue (vmcnt counted manually in the K-loop) ----
__device__ __forceinline__ void ld_coh(short8* a, const unsigned short* p) {   // device-coherent
    asm volatile("global_load_dwordx4 %0, %1, off sc0 sc1" : "=&v"(*a) : "v"(p) : "memory");
}
__device__ __forceinline__ void ld_pln(short8* a, const unsigned short* p) {   // cached
    asm volatile("global_load_dwordx4 %0, %1, off" : "=&v"(*a) : "v"(p) : "memory");
}
__device__ __forceinline__ void st_coh_u16(unsigned short* p, unsigned short v) {
    asm volatile("global_store_short %0, %1, off sc0 sc1" :: "v"(p), "v"((unsigned)v) : "memory");
}
#define WAIT_VM(N) do { asm volatile("s_waitcnt vmcnt(" #N ")" ::: "memory"); \
                        __builtin_amdgcn_sched_barrier(0); } while (0)

// Persistent fused 2-layer GRU. 256 blocks x 512 thr (8 waves = 2/SIMD), one
// block/CU. Coherence: hb (cross-block h state) via sc0sc1 write-through
// stores + bypass loads -> NO cache fences anywhere. hf/out/xb/weights are
// block-private or read-only -> plain cached. Weights in VGPRs (K-eighth/wave).
template<int LAYER>
__device__ __forceinline__ void gru_loop(
    const unsigned short* __restrict__ xb,
    const unsigned short* __restrict__ Wi, const unsigned short* __restrict__ Wh,
    const float* __restrict__ bi, const float* __restrict__ bh_,
    float* __restrict__ hf, unsigned short* __restrict__ hb,
    float* __restrict__ out, unsigned* __restrict__ bar,
    int bid, float (*lds)[4][3][272])
{
    constexpr int Din = LAYER ? HID : DIN0;
    constexpr int K   = Din + HID;
    constexpr int Kq  = K / 8;               // per-wave K range: 192 or 256
    constexpr int NK  = Kq / 32;             // 6 or 8 K-steps per wave

    const int j0  = (bid & 127) << 3;
    const int tid = threadIdx.x;
    const int l   = tid & 63;
    const int w   = tid >> 6;                // wave id 0..7 = K-eighth
    const int c   = l & 15;                  // frag col / A row
    const int kg  = l >> 4;                  // k subgroup
    const int kq0 = w * Kq;

    // ---- one-time: weight B-frags into registers (48 or 64 VGPRs) ----
    // tile0 packs [r | z] (col<8 -> r row, col>=8 -> z row); tile1 = n gate.
    const int row0 = ((c < 8) ? 0 : HID) + j0 + (c & 7);
    const int row1 = 2 * HID + j0 + (c & 7);
    short8 Bw0[NK], Bw1[NK];
#pragma unroll
    for (int s = 0; s < NK; ++s) {
        const int k0 = kq0 + s * 32 + kg * 8;
        const unsigned short *p0, *p1;
        if (k0 < Din) { p0 = Wi + (long)row0 * Din + k0;         p1 = Wi + (long)row1 * Din + k0; }
        else          { p0 = Wh + (long)row0 * HID + (k0 - Din); p1 = Wh + (long)row1 * HID + (k0 - Din); }
        Bw0[s] = *(const short8*)p0;
        Bw1[s] = *(const short8*)p1;
    }

    // per-m row offsets (loop-invariant)
    long xrow[4], hrow[4];
#pragma unroll
    for (int m = 0; m < 4; ++m) {
        xrow[m] = (long)(m * 16 + c) * SEQ * DIN0;
        hrow[m] = (long)(m * 16 + c) * HID;
    }

    // ---- combine-phase loop invariants: thread -> (batch cb, col j0+jc) ----
    const int cb  = tid >> 3;                // 0..63
    const int jc  = tid & 7;
    const int cm  = cb >> 4, cbr = cb & 15;
    const int j   = j0 + jc;
    const float bir = bi[j], biz = bi[HID + j], bin = bi[2 * HID + j];
    const float bhr = bh_[j], bhz = bh_[HID + j], bhn = bh_[2 * HID + j];

    for (int i = 0; i <= SEQ; ++i) {
        const int st = LAYER ? (i - 1) : i;
        if (st >= 0 && st < SEQ) {
            const int rp = st & 1, wp = rp ^ 1;
            const unsigned short* Alo = hb + (long)(0 * 2 + wp) * NB * HID;      // L1: out0(st)
            const unsigned short* Ahi = hb + (long)(LAYER * 2 + rp) * NB * HID;  // own h(st-1)
            const long xbase = (long)st * DIN0;

            f32x4 acc_rz[4], acc_nx[4], acc_nh[4];
#pragma unroll
            for (int m = 0; m < 4; ++m) {
                acc_rz[m] = (f32x4){0.f, 0.f, 0.f, 0.f};
                acc_nx[m] = (f32x4){0.f, 0.f, 0.f, 0.f};
                acc_nh[m] = (f32x4){0.f, 0.f, 0.f, 0.f};
            }

            short8 abuf[2][4];
            // issue group 0
            {
                const int kk = kq0 + kg * 8;
                if (LAYER == 0 && kq0 < Din) {
#pragma unroll
                    for (int m = 0; m < 4; ++m) ld_pln(&abuf[0][m], xb + xrow[m] + xbase + kk);
                } else if (LAYER == 0) {
#pragma unroll
                    for (int m = 0; m < 4; ++m) ld_coh(&abuf[0][m], Ahi + hrow[m] + (kk - DIN0));
                } else {
                    const unsigned short* base = (kq0 < Din) ? (Alo + kk) : (Ahi + (kk - HID));
#pragma unroll
                    for (int m = 0; m < 4; ++m) ld_coh(&abuf[0][m], base + hrow[m]);
                }
            }
#pragma unroll
            for (int s = 0; s < NK; ++s) {
                if (s + 1 < NK) {   // issue group s+1 before waiting on s
                    const int kk = kq0 + (s + 1) * 32 + kg * 8;
                    const bool lo = (kq0 + (s + 1) * 32) < Din;
                    if (LAYER == 0 && lo) {
#pragma unroll
                        for (int m = 0; m < 4; ++m) ld_pln(&abuf[(s + 1) & 1][m], xb + xrow[m] + xbase + kk);
                    } else if (LAYER == 0) {
#pragma unroll
                        for (int m = 0; m < 4; ++m) ld_coh(&abuf[(s + 1) & 1][m], Ahi + hrow[m] + (kk - DIN0));
                    } else {
                        const unsigned short* base = lo ? (Alo + kk) : (Ahi + (kk - HID));
#pragma unroll
                        for (int m = 0; m < 4; ++m) ld_coh(&abuf[(s + 1) & 1][m], base + hrow[m]);
                    }
                    WAIT_VM(4);
                } else {
                    WAIT_VM(0);
                }
                const bool lo = (kq0 + s * 32) < Din;    // wave-uniform
#pragma unroll
                for (int m = 0; m < 4; ++m)
                    acc_rz[m] = __builtin_amdgcn_mfma_f32_16x16x32_bf16(abuf[s & 1][m], Bw0[s], acc_rz[m], 0, 0, 0);
                if (lo) {
#pragma unroll
                    for (int m = 0; m < 4; ++m)
                        acc_nx[m] = __builtin_amdgcn_mfma_f32_16x16x32_bf16(abuf[s & 1][m], Bw1[s], acc_nx[m], 0, 0, 0);
                } else {
#pragma unroll
                    for (int m = 0; m < 4; ++m)
                        acc_nh[m] = __builtin_amdgcn_mfma_f32_16x16x32_bf16(abuf[s & 1][m], Bw1[s], acc_nh[m], 0, 0, 0);
                }
            }

            // ---- two-phase cross-wave reduction in LDS (52 KB) ----
            if (w >= 4) {
#pragma unroll
                for (int m = 0; m < 4; ++m)
#pragma unroll
                    for (int v = 0; v < 4; ++v) {
                        const int rc = (kg * 4 + v) * 17 + c;  // C/D: row=(l>>4)*4+v, col=l&15
                        lds[w - 4][m][0][rc] = acc_rz[m][v];
                        lds[w - 4][m][1][rc] = acc_nx[m][v];
                        lds[w - 4][m][2][rc] = acc_nh[m][v];
                    }
            }
            __syncthreads();
            if (w < 4) {
#pragma unroll
                for (int m = 0; m < 4; ++m)
#pragma unroll
                    for (int v = 0; v < 4; ++v) {
                        const int rc = (kg * 4 + v) * 17 + c;
                        lds[w][m][0][rc] += acc_rz[m][v];
                        lds[w][m][1][rc] += acc_nx[m][v];
                        lds[w][m][2][rc] += acc_nh[m][v];
                    }
            }
            __syncthreads();

            // ---- combine 4 pairwise sums + pointwise: 1 item/thread ----
            float rr = 0.f, zz = 0.f, nx = 0.f, nh = 0.f;
#pragma unroll
            for (int ww = 0; ww < 4; ++ww) {
                rr += lds[ww][cm][0][cbr * 17 + jc];
                zz += lds[ww][cm][0][cbr * 17 + 8 + jc];
                nx += lds[ww][cm][1][cbr * 17 + jc];
                nh += lds[ww][cm][2][cbr * 17 + jc];
            }
            const float r = sigm_(rr + bir + bhr);
            const float z = sigm_(zz + biz + bhz);
            const float n = tanh_((nx + bin) + r * (nh + bhn));
            const long pofs = ((long)(LAYER * 2 + rp) * NB + cb) * HID + j;
            const long nofs = ((long)(LAYER * 2 + wp) * NB + cb) * HID + j;
            const float hp = hf[pofs];                     // block-private, cached
            const float hnew = (1.f - z) * hp + z * n;
            hf[nofs] = hnew;
            st_coh_u16(hb + nofs, f2bf(hnew));             // device-visible h state
            if (LAYER) out[((long)cb * SEQ + st) * HID + j] = hnew;
            __syncthreads();   // lds safe for next interval's phase-1 writes
        }

        // ---- grid barrier: plain atomic tree, no cache fences ----
        asm volatile("s_waitcnt vmcnt(0)" ::: "memory");   // hb write-through complete
        __syncthreads();
        if (tid == 0) {
            unsigned* gen  = bar;
            unsigned* root = bar + 16;
            unsigned* sub  = bar + 32 + (bid & 7) * 16;
            unsigned g = __hip_atomic_load(gen, __ATOMIC_RELAXED, __HIP_MEMORY_SCOPE_AGENT);
            if (__hip_atomic_fetch_add(sub, 1u, __ATOMIC_RELAXED, __HIP_MEMORY_SCOPE_AGENT) == 31u) {
                __hip_atomic_store(sub, 0u, __ATOMIC_RELAXED, __HIP_MEMORY_SCOPE_AGENT);
                asm volatile("s_waitcnt vmcnt(0)" ::: "memory");  // reset lands before root add
                if (__hip_atomic_fetch_add(root, 1u, __ATOMIC_RELAXED, __HIP_MEMORY_SCOPE_AGENT) == 7u) {
                    __hip_atomic_store(root, 0u, __ATOMIC_RELAXED, __HIP_MEMORY_SCOPE_AGENT);
                    asm volatile("s_waitcnt vmcnt(0)" ::: "memory");
                    __hip_atomic_fetch_add(gen, 1u, __ATOMIC_RELAXED, __HIP_MEMORY_SCOPE_AGENT);
                }
            }
            while (__hip_atomic_load(gen, __ATOMIC_RELAXED, __HIP_MEMORY_SCOPE_AGENT) == g)
                __builtin_amdgcn_s_sleep(2);
        }
        __syncthreads();
    }
}

__global__ __launch_bounds__(512, 2) void gru_persist(
    const unsigned short* __restrict__ xb,
    const unsigned short* __restrict__ W0i, const unsigned short* __restrict__ W0h,
    const unsigned short* __restrict__ W1i, const unsigned short* __restrict__ W1h,
    const float* __restrict__ bi0, const float* __restrict__ bh0,
    const float* __restrict__ bi1, const float* __restrict__ bh1,
    float* __restrict__ hf, unsigned short* __restrict__ hb,
    float* __restrict__ out, unsigned* __restrict__ bar)
{
    __shared__ float lds[4][4][3][272];   // [wavepair][m][rz|nx|nh][16 rows x 17]
    const int bid = blockIdx.x;
    if (bid < 128) gru_loop<0>(xb, W0i, W0h, bi0, bh0, hf, hb, out, bar, bid, lds);
    else           gru_loop<1>(xb, W1i, W1h, bi1, bh1, hf, hb, out, bar, bid, lds);
}

__global__ __launch_bounds__(256) void cvt_bf16(const float* __restrict__ src,
                                                unsigned short* __restrict__ dst, int n4) {
    int i = blockIdx.x * 256 + threadIdx.x;
    if (i >= n4) return;
    float4 f = *(const float4*)(src + 4L * i);
    unsigned long long u =  (unsigned long long)f2bf(f.x)
                         | ((unsigned long long)f2bf(f.y) << 16)
                         | ((unsigned long long)f2bf(f.z) << 32)
                         | ((unsigned long long)f2bf(f.w) << 48);
    *(unsigned long long*)(dst + 4L * i) = u;
}

__global__ __launch_bounds__(256) void init_h(const float* __restrict__ h0,
                                              float* __restrict__ hf,
                                              unsigned short* __restrict__ hb) {
    int i = blockIdx.x * 256 + threadIdx.x;          // 2*64*1024 threads
    int layer = i >> 16, idx = i & 65535;
    float v = h0[i];
    hf[(long)(layer * 2 + 0) * 65536 + idx] = v;     // parity 0
    hb[(long)(layer * 2 + 0) * 65536 + idx] = f2bf(v);
}

extern "C" void kernel_launch(void* const* d_in, const int* in_sizes, int n_in,
                              void* d_out, int out_size, void* d_ws, size_t ws_size,
                              hipStream_t stream) {
    const float* x    = (const float*)d_in[0];
    const float* h0   = (const float*)d_in[1];
    const float* Wih0 = (const float*)d_in[2];
    const float* Whh0 = (const float*)d_in[3];
    const float* bih0 = (const float*)d_in[4];
    const float* bhh0 = (const float*)d_in[5];
    const float* Wih1 = (const float*)d_in[6];
    const float* Whh1 = (const float*)d_in[7];
    const float* bih1 = (const float*)d_in[8];
    const float* bhh1 = (const float*)d_in[9];

    float* out   = (float*)d_out;                    // [64][512][1024]
    float* hnout = out + (long)NB * SEQ * HID;       // [2][64][1024]

    // ws layout (~56 MiB):
    unsigned short* W0i = (unsigned short*)d_ws;             // [3072][512]
    unsigned short* W0h = W0i + 3072L * 512;                 // [3072][1024]
    unsigned short* W1i = W0h + 3072L * 1024;
    unsigned short* W1h = W1i + 3072L * 1024;
    float*          hf  = (float*)(W1h + 3072L * 1024);      // [2][2][64][1024] f32
    unsigned short* hb  = (unsigned short*)(hf + 4L * 65536);
    unsigned*       bar = (unsigned*)(hb + 4L * 65536);      // barrier lines (1 KB)
    unsigned short* xb  = (unsigned short*)(bar + 256);      // [64][512][512] bf16

    // barrier counters MUST be zero each call (ws is poisoned before timing)
    hipMemsetAsync(bar, 0, 1024, stream);

    cvt_bf16<<<(3072 * 512 / 4  + 255) / 256, 256, 0, stream>>>(Wih0, W0i, 3072 * 512 / 4);
    cvt_bf16<<<(3072 * 1024 / 4 + 255) / 256, 256, 0, stream>>>(Whh0, W0h, 3072 * 1024 / 4);
    cvt_bf16<<<(3072 * 1024 / 4 + 255) / 256, 256, 0, stream>>>(Wih1, W1i, 3072 * 1024 / 4);
    cvt_bf16<<<(3072 * 1024 / 4 + 255) / 256, 256, 0, stream>>>(Whh1, W1h, 3072 * 1024 / 4);
    cvt_bf16<<<(NB * SEQ * DIN0 / 4 + 255) / 256, 256, 0, stream>>>(x, xb, NB * SEQ * DIN0 / 4);
    init_h<<<512, 256, 0, stream>>>(h0, hf, hb);

    gru_persist<<<256, 512, 0, stream>>>(xb, W0i, W0h, W1i, W1h,
                                         bih0, bhh0, bih1, bhh1,
                                         hf, hb, out, bar);

    // both layers' t=511 state lands in parity 0
    hipMemcpyAsync(hnout,         hf,              65536 * sizeof(float),
                   hipMemcpyDeviceToDevice, stream);
    hipMemcpyAsync(hnout + 65536, hf + 2L * 65536, 65536 * sizeof(float),
                   hipMemcpyDeviceToDevice, stream);
}

// Round 8
// 3975.085 us; speedup vs baseline: 12.4987x; 1.6141x over previous
//
#include <hip/hip_runtime.h>
#include <math.h>

#define HID  1024
#define SEQ  512
#define NB   64
#define DIN0 512

using short8 = __attribute__((ext_vector_type(8))) short;
using f32x4  = __attribute__((ext_vector_type(4))) float;

__device__ __forceinline__ unsigned short f2bf(float f) {
    unsigned int u = __float_as_uint(f);
    u += 0x7fffu + ((u >> 16) & 1u);          // round-to-nearest-even
    return (unsigned short)(u >> 16);
}
__device__ __forceinline__ float sigm_(float x) { return 1.0f / (1.0f + __expf(-x)); }
__device__ __forceinline__ float tanh_(float x) {
    float ax = fabsf(x);
    float e = __expf(-2.0f * ax);
    float t = (1.0f - e) / (1.0f + e);
    return copysignf(t, x);
}

// ---- no-wait load issue (vmcnt counted manually in the K-loop) ----
__device__ __forceinline__ void ld_coh(short8* a, const unsigned short* p) {   // device-coherent
    asm volatile("global_load_dwordx4 %0, %1, off sc0 sc1" : "=&v"(*a) : "v"(p) : "memory");
}
__device__ __forceinline__ void ld_pln(short8* a, const unsigned short* p) {   // cached
    asm volatile("global_load_dwordx4 %0, %1, off" : "=&v"(*a) : "v"(p) : "memory");
}
__device__ __forceinline__ void st_coh_u16(unsigned short* p, unsigned short v) {
    asm volatile("global_store_short %0, %1, off sc0 sc1" :: "v"(p), "v"((unsigned)v) : "memory");
}

// Persistent fused 2-layer GRU. 256 blocks x 512 thr (8 waves = 2/SIMD),
// 1 block/CU. Block = [32 batches x 16 j-cols] tile (batch-split halves the
// coherent A-broadcast vs 64x8). Coherence: hb via sc0sc1 write-through +
// bypass loads; NO cache fences. Weights in VGPRs (K-eighth per wave,
// 3 gates x NK x 4 VGPR). A-loads: 4-deep ring, literal-counted vmcnt.
template<int LAYER>
__device__ __forceinline__ void gru_loop(
    const unsigned short* __restrict__ xb,
    const unsigned short* __restrict__ Wi, const unsigned short* __restrict__ Wh,
    const float* __restrict__ bi, const float* __restrict__ bh_,
    float* __restrict__ hf, unsigned short* __restrict__ hb,
    float* __restrict__ out, unsigned* __restrict__ bar,
    int bid, float (*lds)[2][4][272])
{
    constexpr int Din = LAYER ? HID : DIN0;
    constexpr int K   = Din + HID;
    constexpr int Kq  = K / 8;               // per-wave K range: 192 or 256
    constexpr int NK  = Kq / 32;             // 6 or 8 K-steps per wave

    const int q   = bid & 127;
    const int j0  = (q >> 1) << 4;           // 16-col j slice
    const int b0  = (q & 1) << 5;            // batch half: 0 or 32
    const int tid = threadIdx.x;
    const int l   = tid & 63;
    const int w   = tid >> 6;                // wave id 0..7 = K-eighth
    const int c   = l & 15;                  // frag col / A row
    const int kg  = l >> 4;                  // k subgroup
    const int kq0 = w * Kq;

    // ---- one-time: weight B-frags into registers (72 or 96 VGPRs) ----
    short8 Br[NK], Bz[NK], Bn[NK];
#pragma unroll
    for (int s = 0; s < NK; ++s) {
        const int k0 = kq0 + s * 32 + kg * 8;
        const unsigned short *pr, *pz, *pn;
        if (k0 < Din) {
            pr = Wi + (long)(j0 + c) * Din + k0;
            pz = Wi + (long)(HID + j0 + c) * Din + k0;
            pn = Wi + (long)(2 * HID + j0 + c) * Din + k0;
        } else {
            pr = Wh + (long)(j0 + c) * HID + (k0 - Din);
            pz = Wh + (long)(HID + j0 + c) * HID + (k0 - Din);
            pn = Wh + (long)(2 * HID + j0 + c) * HID + (k0 - Din);
        }
        Br[s] = *(const short8*)pr;
        Bz[s] = *(const short8*)pz;
        Bn[s] = *(const short8*)pn;
    }

    const long hrow0 = (long)(b0 + c) * HID;        // A rows for m=0 / m=1
    const long hrow1 = (long)(b0 + 16 + c) * HID;
    const long xrow0 = (long)(b0 + c) * SEQ * DIN0;
    const long xrow1 = (long)(b0 + 16 + c) * SEQ * DIN0;

    // ---- combine-phase invariants: thread -> (batch b0+cb, col j0+jc) ----
    const int cb  = tid >> 4;                // 0..31
    const int jc  = tid & 15;
    const int cm  = cb >> 4, cbr = cb & 15;
    const int j   = j0 + jc;
    const float bir = bi[j], biz = bi[HID + j], bin = bi[2 * HID + j];
    const float bhr = bh_[j], bhz = bh_[HID + j], bhn = bh_[2 * HID + j];

    for (int i = 0; i <= SEQ; ++i) {
        const int st = LAYER ? (i - 1) : i;
        if (st >= 0 && st < SEQ) {
            const int rp = st & 1, wp = rp ^ 1;
            const unsigned short* Alo = hb + (long)(0 * 2 + wp) * NB * HID;      // L1: out0(st)
            const unsigned short* Ahi = hb + (long)(LAYER * 2 + rp) * NB * HID;  // own h(st-1)
            const unsigned short* xp0 = xb + xrow0 + (long)st * DIN0;
            const unsigned short* xp1 = xb + xrow1 + (long)st * DIN0;

            f32x4 acc_r[2], acc_z[2], acc_nx[2], acc_nh[2];
#pragma unroll
            for (int m = 0; m < 2; ++m) {
                acc_r[m] = (f32x4){0.f, 0.f, 0.f, 0.f};
                acc_z[m] = (f32x4){0.f, 0.f, 0.f, 0.f};
                acc_nx[m] = (f32x4){0.f, 0.f, 0.f, 0.f};
                acc_nh[m] = (f32x4){0.f, 0.f, 0.f, 0.f};
            }

            short8 abuf[4][2];   // 4-deep ring x 2 m-tiles

#define ISSUE(g) do {                                                          \
    const int kk_ = kq0 + (g) * 32 + kg * 8;                                   \
    const bool lo_ = (kq0 + (g) * 32) < Din;                                   \
    if (LAYER == 0) {                                                          \
        if (lo_) { ld_pln(&abuf[(g) & 3][0], xp0 + kk_);                       \
                   ld_pln(&abuf[(g) & 3][1], xp1 + kk_); }                     \
        else     { ld_coh(&abuf[(g) & 3][0], Ahi + hrow0 + (kk_ - Din));       \
                   ld_coh(&abuf[(g) & 3][1], Ahi + hrow1 + (kk_ - Din)); }     \
    } else {                                                                   \
        const unsigned short* bse_ = lo_ ? (Alo + kk_) : (Ahi + (kk_ - HID));  \
        ld_coh(&abuf[(g) & 3][0], bse_ + hrow0);                               \
        ld_coh(&abuf[(g) & 3][1], bse_ + hrow1);                               \
    } } while (0)

#define MSTEP(s) do {                                                                                  \
    const bool lo_ = (kq0 + (s) * 32) < Din;                                                           \
    acc_r[0] = __builtin_amdgcn_mfma_f32_16x16x32_bf16(abuf[(s) & 3][0], Br[s], acc_r[0], 0, 0, 0);    \
    acc_r[1] = __builtin_amdgcn_mfma_f32_16x16x32_bf16(abuf[(s) & 3][1], Br[s], acc_r[1], 0, 0, 0);    \
    acc_z[0] = __builtin_amdgcn_mfma_f32_16x16x32_bf16(abuf[(s) & 3][0], Bz[s], acc_z[0], 0, 0, 0);    \
    acc_z[1] = __builtin_amdgcn_mfma_f32_16x16x32_bf16(abuf[(s) & 3][1], Bz[s], acc_z[1], 0, 0, 0);    \
    if (lo_) {                                                                                         \
        acc_nx[0] = __builtin_amdgcn_mfma_f32_16x16x32_bf16(abuf[(s) & 3][0], Bn[s], acc_nx[0], 0, 0, 0); \
        acc_nx[1] = __builtin_amdgcn_mfma_f32_16x16x32_bf16(abuf[(s) & 3][1], Bn[s], acc_nx[1], 0, 0, 0); \
    } else {                                                                                           \
        acc_nh[0] = __builtin_amdgcn_mfma_f32_16x16x32_bf16(abuf[(s) & 3][0], Bn[s], acc_nh[0], 0, 0, 0); \
        acc_nh[1] = __builtin_amdgcn_mfma_f32_16x16x32_bf16(abuf[(s) & 3][1], Bn[s], acc_nh[1], 0, 0, 0); \
    } } while (0)

#define KSTEP(s, W) do {                                                       \
    if ((s) + 3 < NK) ISSUE((s) + 3);                                          \
    asm volatile("s_waitcnt vmcnt(" #W ")" ::: "memory");                      \
    __builtin_amdgcn_sched_barrier(0);                                         \
    MSTEP(s); } while (0)

            ISSUE(0); ISSUE(1); ISSUE(2);
            if constexpr (NK == 8) {
                KSTEP(0, 6); KSTEP(1, 6); KSTEP(2, 6); KSTEP(3, 6);
                KSTEP(4, 6); KSTEP(5, 4); KSTEP(6, 2); KSTEP(7, 0);
            } else {
                KSTEP(0, 6); KSTEP(1, 6); KSTEP(2, 6);
                KSTEP(3, 4); KSTEP(4, 2); KSTEP(5, 0);
            }
#undef ISSUE
#undef MSTEP
#undef KSTEP

            // ---- two-phase cross-wave reduction in LDS (~35 KB) ----
            if (w >= 4) {
#pragma unroll
                for (int m = 0; m < 2; ++m)
#pragma unroll
                    for (int v = 0; v < 4; ++v) {
                        const int rc = (kg * 4 + v) * 17 + c;   // C/D: row=(l>>4)*4+v, col=l&15
                        lds[w - 4][m][0][rc] = acc_r[m][v];
                        lds[w - 4][m][1][rc] = acc_z[m][v];
                        lds[w - 4][m][2][rc] = acc_nx[m][v];
                        lds[w - 4][m][3][rc] = acc_nh[m][v];
                    }
            }
            __syncthreads();
            if (w < 4) {
#pragma unroll
                for (int m = 0; m < 2; ++m)
#pragma unroll
                    for (int v = 0; v < 4; ++v) {
                        const int rc = (kg * 4 + v) * 17 + c;
                        lds[w][m][0][rc] += acc_r[m][v];
                        lds[w][m][1][rc] += acc_z[m][v];
                        lds[w][m][2][rc] += acc_nx[m][v];
                        lds[w][m][3][rc] += acc_nh[m][v];
                    }
            }
            __syncthreads();

            // ---- combine 4 pairwise sums + pointwise: 1 item/thread ----
            float rr = 0.f, zz = 0.f, nx = 0.f, nh = 0.f;
#pragma unroll
            for (int ww = 0; ww < 4; ++ww) {
                rr += lds[ww][cm][0][cbr * 17 + jc];
                zz += lds[ww][cm][1][cbr * 17 + jc];
                nx += lds[ww][cm][2][cbr * 17 + jc];
                nh += lds[ww][cm][3][cbr * 17 + jc];
            }
            const float r = sigm_(rr + bir + bhr);
            const float z = sigm_(zz + biz + bhz);
            const float n = tanh_((nx + bin) + r * (nh + bhn));
            const int bgl = b0 + cb;                       // global batch
            const long pofs = ((long)(LAYER * 2 + rp) * NB + bgl) * HID + j;
            const long nofs = ((long)(LAYER * 2 + wp) * NB + bgl) * HID + j;
            const float hp = hf[pofs];                     // block-private, cached
            const float hnew = (1.f - z) * hp + z * n;
            hf[nofs] = hnew;
            st_coh_u16(hb + nofs, f2bf(hnew));             // device-visible h state
            if (LAYER) out[((long)bgl * SEQ + st) * HID + j] = hnew;
        }

        // ---- grid barrier: atomic tree, replicated gen lines, no fences ----
        asm volatile("s_waitcnt vmcnt(0)" ::: "memory");   // hb write-through complete
        __syncthreads();
        if (tid == 0) {
            unsigned* gen = bar + (bid & 7) * 16;          // this block's gen copy
            unsigned* sub = bar + 160 + (bid & 7) * 16;
            unsigned g = __hip_atomic_load(gen, __ATOMIC_RELAXED, __HIP_MEMORY_SCOPE_AGENT);
            if (__hip_atomic_fetch_add(sub, 1u, __ATOMIC_RELAXED, __HIP_MEMORY_SCOPE_AGENT) == 31u) {
                __hip_atomic_store(sub, 0u, __ATOMIC_RELAXED, __HIP_MEMORY_SCOPE_AGENT);
                asm volatile("s_waitcnt vmcnt(0)" ::: "memory");  // reset lands before root add
                unsigned* root = bar + 128;
                if (__hip_atomic_fetch_add(root, 1u, __ATOMIC_RELAXED, __HIP_MEMORY_SCOPE_AGENT) == 7u) {
                    __hip_atomic_store(root, 0u, __ATOMIC_RELAXED, __HIP_MEMORY_SCOPE_AGENT);
                    asm volatile("s_waitcnt vmcnt(0)" ::: "memory");
#pragma unroll
                    for (int gg = 0; gg < 8; ++gg)
                        __hip_atomic_fetch_add(bar + gg * 16, 1u, __ATOMIC_RELAXED, __HIP_MEMORY_SCOPE_AGENT);
                }
            }
            while (__hip_atomic_load(gen, __ATOMIC_RELAXED, __HIP_MEMORY_SCOPE_AGENT) == g)
                __builtin_amdgcn_s_sleep(2);
        }
        __syncthreads();
    }
}

__global__ __launch_bounds__(512, 2) void gru_persist(
    const unsigned short* __restrict__ xb,
    const unsigned short* __restrict__ W0i, const unsigned short* __restrict__ W0h,
    const unsigned short* __restrict__ W1i, const unsigned short* __restrict__ W1h,
    const float* __restrict__ bi0, const float* __restrict__ bh0,
    const float* __restrict__ bi1, const float* __restrict__ bh1,
    float* __restrict__ hf, unsigned short* __restrict__ hb,
    float* __restrict__ out, unsigned* __restrict__ bar)
{
    __shared__ float lds[4][2][4][272];   // [wavepair][m][r|z|nx|nh][16 rows x 17]
    const int bid = blockIdx.x;
    if (bid < 128) gru_loop<0>(xb, W0i, W0h, bi0, bh0, hf, hb, out, bar, bid, lds);
    else           gru_loop<1>(xb, W1i, W1h, bi1, bh1, hf, hb, out, bar, bid, lds);
}

__global__ __launch_bounds__(256) void cvt_bf16(const float* __restrict__ src,
                                                unsigned short* __restrict__ dst, int n4) {
    int i = blockIdx.x * 256 + threadIdx.x;
    if (i >= n4) return;
    float4 f = *(const float4*)(src + 4L * i);
    unsigned long long u =  (unsigned long long)f2bf(f.x)
                         | ((unsigned long long)f2bf(f.y) << 16)
                         | ((unsigned long long)f2bf(f.z) << 32)
                         | ((unsigned long long)f2bf(f.w) << 48);
    *(unsigned long long*)(dst + 4L * i) = u;
}

__global__ __launch_bounds__(256) void init_h(const float* __restrict__ h0,
                                              float* __restrict__ hf,
                                              unsigned short* __restrict__ hb) {
    int i = blockIdx.x * 256 + threadIdx.x;          // 2*64*1024 threads
    int layer = i >> 16, idx = i & 65535;
    float v = h0[i];
    hf[(long)(layer * 2 + 0) * 65536 + idx] = v;     // parity 0
    hb[(long)(layer * 2 + 0) * 65536 + idx] = f2bf(v);
}

extern "C" void kernel_launch(void* const* d_in, const int* in_sizes, int n_in,
                              void* d_out, int out_size, void* d_ws, size_t ws_size,
                              hipStream_t stream) {
    const float* x    = (const float*)d_in[0];
    const float* h0   = (const float*)d_in[1];
    const float* Wih0 = (const float*)d_in[2];
    const float* Whh0 = (const float*)d_in[3];
    const float* bih0 = (const float*)d_in[4];
    const float* bhh0 = (const float*)d_in[5];
    const float* Wih1 = (const float*)d_in[6];
    const float* Whh1 = (const float*)d_in[7];
    const float* bih1 = (const float*)d_in[8];
    const float* bhh1 = (const float*)d_in[9];

    float* out   = (float*)d_out;                    // [64][512][1024]
    float* hnout = out + (long)NB * SEQ * HID;       // [2][64][1024]

    // ws layout (~56 MiB):
    unsigned short* W0i = (unsigned short*)d_ws;             // [3072][512]
    unsigned short* W0h = W0i + 3072L * 512;                 // [3072][1024]
    unsigned short* W1i = W0h + 3072L * 1024;
    unsigned short* W1h = W1i + 3072L * 1024;
    float*          hf  = (float*)(W1h + 3072L * 1024);      // [2][2][64][1024] f32
    unsigned short* hb  = (unsigned short*)(hf + 4L * 65536);
    unsigned*       bar = (unsigned*)(hb + 4L * 65536);      // barrier lines (2 KB)
    unsigned short* xb  = (unsigned short*)(bar + 512);      // [64][512][512] bf16

    // barrier counters MUST be zero each call (ws is poisoned before timing)
    hipMemsetAsync(bar, 0, 2048, stream);

    cvt_bf16<<<(3072 * 512 / 4  + 255) / 256, 256, 0, stream>>>(Wih0, W0i, 3072 * 512 / 4);
    cvt_bf16<<<(3072 * 1024 / 4 + 255) / 256, 256, 0, stream>>>(Whh0, W0h, 3072 * 1024 / 4);
    cvt_bf16<<<(3072 * 1024 / 4 + 255) / 256, 256, 0, stream>>>(Wih1, W1i, 3072 * 1024 / 4);
    cvt_bf16<<<(3072 * 1024 / 4 + 255) / 256, 256, 0, stream>>>(Whh1, W1h, 3072 * 1024 / 4);
    cvt_bf16<<<(NB * SEQ * DIN0 / 4 + 255) / 256, 256, 0, stream>>>(x, xb, NB * SEQ * DIN0 / 4);
    init_h<<<512, 256, 0, stream>>>(h0, hf, hb);

    gru_persist<<<256, 512, 0, stream>>>(xb, W0i, W0h, W1i, W1h,
                                         bih0, bhh0, bih1, bhh1,
                                         hf, hb, out, bar);

    // both layers' t=511 state lands in parity 0
    hipMemcpyAsync(hnout,         hf,              65536 * sizeof(float),
                   hipMemcpyDeviceToDevice, stream);
    hipMemcpyAsync(hnout + 65536, hf + 2L * 65536, 65536 * sizeof(float),
                   hipMemcpyDeviceToDevice, stream);
}

// Round 9
// 3290.711 us; speedup vs baseline: 15.0980x; 1.2080x over previous
//
#include <hip/hip_runtime.h>
#include <math.h>

#define HID  1024
#define SEQ  512
#define NB   64
#define DIN0 512

using short8 = __attribute__((ext_vector_type(8))) short;
using f32x4  = __attribute__((ext_vector_type(4))) float;

__device__ __forceinline__ unsigned short f2bf(float f) {
    unsigned int u = __float_as_uint(f);
    u += 0x7fffu + ((u >> 16) & 1u);          // round-to-nearest-even
    return (unsigned short)(u >> 16);
}
__device__ __forceinline__ float sigm_(float x) { return 1.0f / (1.0f + __expf(-x)); }
__device__ __forceinline__ float tanh_(float x) {
    float ax = fabsf(x);
    float e = __expf(-2.0f * ax);
    float t = (1.0f - e) / (1.0f + e);
    return copysignf(t, x);
}

// ---- no-wait load issue (vmcnt counted manually in the K-loop) ----
__device__ __forceinline__ void ld_coh(short8* a, const unsigned short* p) {   // device-coherent
    asm volatile("global_load_dwordx4 %0, %1, off sc0 sc1" : "=&v"(*a) : "v"(p) : "memory");
}
__device__ __forceinline__ void ld_pln(short8* a, const unsigned short* p) {   // cached
    asm volatile("global_load_dwordx4 %0, %1, off" : "=&v"(*a) : "v"(p) : "memory");
}
__device__ __forceinline__ void st_coh_u16(unsigned short* p, unsigned short v) {
    asm volatile("global_store_short %0, %1, off sc0 sc1" :: "v"(p), "v"((unsigned)v) : "memory");
}

// Persistent fused 2-layer GRU. 256 blocks x 512 thr (8 waves = 2/SIMD),
// 1 block/CU. Block = [32 batches x 16 j-cols]. Coherence: hb via sc0sc1
// write-through + bypass loads; NO cache fences, NO atomics. Weights in VGPRs
// (K-eighth per wave). Barrier: per-block flag stores + block-0 checker.
template<int LAYER>
__device__ __forceinline__ void gru_loop(
    const unsigned short* __restrict__ xb,
    const unsigned short* __restrict__ Wi, const unsigned short* __restrict__ Wh,
    const float* __restrict__ bi, const float* __restrict__ bh_,
    float* __restrict__ hf, unsigned short* __restrict__ hb,
    float* __restrict__ out, unsigned* __restrict__ bar,
    int bid, float (*lds)[2][16][68])
{
    constexpr int Din = LAYER ? HID : DIN0;
    constexpr int K   = Din + HID;
    constexpr int Kq  = K / 8;               // per-wave K range: 192 or 256
    constexpr int NK  = Kq / 32;             // 6 or 8 K-steps per wave

    const int q   = bid & 127;
    const int j0  = (q >> 1) << 4;           // 16-col j slice
    const int b0  = (q & 1) << 5;            // batch half: 0 or 32
    const int tid = threadIdx.x;
    const int l   = tid & 63;
    const int w   = tid >> 6;                // wave id 0..7 = K-eighth
    const int c   = l & 15;                  // frag col / A row
    const int kg  = l >> 4;                  // k subgroup
    const int kq0 = w * Kq;

    unsigned* gens  = bar;                   // 8 gen lines, stride 16 u32
    unsigned* flags = bar + 128;             // 256 per-block flags

    // ---- one-time: weight B-frags into registers (72 or 96 VGPRs) ----
    short8 Br[NK], Bz[NK], Bn[NK];
#pragma unroll
    for (int s = 0; s < NK; ++s) {
        const int k0 = kq0 + s * 32 + kg * 8;
        const unsigned short *pr, *pz, *pn;
        if (k0 < Din) {
            pr = Wi + (long)(j0 + c) * Din + k0;
            pz = Wi + (long)(HID + j0 + c) * Din + k0;
            pn = Wi + (long)(2 * HID + j0 + c) * Din + k0;
        } else {
            pr = Wh + (long)(j0 + c) * HID + (k0 - Din);
            pz = Wh + (long)(HID + j0 + c) * HID + (k0 - Din);
            pn = Wh + (long)(2 * HID + j0 + c) * HID + (k0 - Din);
        }
        Br[s] = *(const short8*)pr;
        Bz[s] = *(const short8*)pz;
        Bn[s] = *(const short8*)pn;
    }

    const long hrow0 = (long)(b0 + c) * HID;        // A rows for m=0 / m=1
    const long hrow1 = (long)(b0 + 16 + c) * HID;
    const long xrow0 = (long)(b0 + c) * SEQ * DIN0;
    const long xrow1 = (long)(b0 + 16 + c) * SEQ * DIN0;

    // ---- combine-phase invariants: thread -> (batch b0+cb, col j0+jc) ----
    const int cb  = tid >> 4;                // 0..31
    const int jc  = tid & 15;
    const int cm  = cb >> 4, cbr = cb & 15;
    const int j   = j0 + jc;
    const float bir = bi[j], biz = bi[HID + j], bin = bi[2 * HID + j];
    const float bhr = bh_[j], bhz = bh_[HID + j], bhn = bh_[2 * HID + j];

    for (int i = 0; i <= SEQ; ++i) {
        const int st = LAYER ? (i - 1) : i;
        if (st >= 0 && st < SEQ) {
            const int rp = st & 1, wp = rp ^ 1;
            const unsigned short* Alo = hb + (long)(0 * 2 + wp) * NB * HID;      // L1: out0(st)
            const unsigned short* Ahi = hb + (long)(LAYER * 2 + rp) * NB * HID;  // own h(st-1)
            const unsigned short* xp0 = xb + xrow0 + (long)st * DIN0;
            const unsigned short* xp1 = xb + xrow1 + (long)st * DIN0;

            f32x4 acc_r[2], acc_z[2], acc_nx[2], acc_nh[2];
#pragma unroll
            for (int m = 0; m < 2; ++m) {
                acc_r[m] = (f32x4){0.f, 0.f, 0.f, 0.f};
                acc_z[m] = (f32x4){0.f, 0.f, 0.f, 0.f};
                acc_nx[m] = (f32x4){0.f, 0.f, 0.f, 0.f};
                acc_nh[m] = (f32x4){0.f, 0.f, 0.f, 0.f};
            }

            short8 abuf[4][2];   // 4-deep ring x 2 m-tiles

#define ISSUE(g) do {                                                          \
    const int kk_ = kq0 + (g) * 32 + kg * 8;                                   \
    const bool lo_ = (kq0 + (g) * 32) < Din;                                   \
    if (LAYER == 0) {                                                          \
        if (lo_) { ld_pln(&abuf[(g) & 3][0], xp0 + kk_);                       \
                   ld_pln(&abuf[(g) & 3][1], xp1 + kk_); }                     \
        else     { ld_coh(&abuf[(g) & 3][0], Ahi + hrow0 + (kk_ - Din));       \
                   ld_coh(&abuf[(g) & 3][1], Ahi + hrow1 + (kk_ - Din)); }     \
    } else {                                                                   \
        const unsigned short* bse_ = lo_ ? (Alo + kk_) : (Ahi + (kk_ - HID));  \
        ld_coh(&abuf[(g) & 3][0], bse_ + hrow0);                               \
        ld_coh(&abuf[(g) & 3][1], bse_ + hrow1);                               \
    } } while (0)

#define MSTEP(s) do {                                                                                  \
    const bool lo_ = (kq0 + (s) * 32) < Din;                                                           \
    acc_r[0] = __builtin_amdgcn_mfma_f32_16x16x32_bf16(abuf[(s) & 3][0], Br[s], acc_r[0], 0, 0, 0);    \
    acc_r[1] = __builtin_amdgcn_mfma_f32_16x16x32_bf16(abuf[(s) & 3][1], Br[s], acc_r[1], 0, 0, 0);    \
    acc_z[0] = __builtin_amdgcn_mfma_f32_16x16x32_bf16(abuf[(s) & 3][0], Bz[s], acc_z[0], 0, 0, 0);    \
    acc_z[1] = __builtin_amdgcn_mfma_f32_16x16x32_bf16(abuf[(s) & 3][1], Bz[s], acc_z[1], 0, 0, 0);    \
    if (lo_) {                                                                                         \
        acc_nx[0] = __builtin_amdgcn_mfma_f32_16x16x32_bf16(abuf[(s) & 3][0], Bn[s], acc_nx[0], 0, 0, 0); \
        acc_nx[1] = __builtin_amdgcn_mfma_f32_16x16x32_bf16(abuf[(s) & 3][1], Bn[s], acc_nx[1], 0, 0, 0); \
    } else {                                                                                           \
        acc_nh[0] = __builtin_amdgcn_mfma_f32_16x16x32_bf16(abuf[(s) & 3][0], Bn[s], acc_nh[0], 0, 0, 0); \
        acc_nh[1] = __builtin_amdgcn_mfma_f32_16x16x32_bf16(abuf[(s) & 3][1], Bn[s], acc_nh[1], 0, 0, 0); \
    } } while (0)

#define KSTEP(s, W) do {                                                       \
    if ((s) + 3 < NK) ISSUE((s) + 3);                                          \
    asm volatile("s_waitcnt vmcnt(" #W ")" ::: "memory");                      \
    __builtin_amdgcn_sched_barrier(0);                                         \
    MSTEP(s); } while (0)

            ISSUE(0); ISSUE(1); ISSUE(2);
            if constexpr (NK == 8) {
                KSTEP(0, 6); KSTEP(1, 6); KSTEP(2, 6); KSTEP(3, 6);
                KSTEP(4, 6); KSTEP(5, 4); KSTEP(6, 2); KSTEP(7, 0);
            } else {
                KSTEP(0, 6); KSTEP(1, 6); KSTEP(2, 6);
                KSTEP(3, 4); KSTEP(4, 2); KSTEP(5, 0);
            }
#undef ISSUE
#undef MSTEP
#undef KSTEP

            // ---- single-phase reduce: every wave writes packed gate quads ----
#pragma unroll
            for (int m = 0; m < 2; ++m)
#pragma unroll
                for (int v = 0; v < 4; ++v) {
                    f32x4 pk = { acc_r[m][v], acc_z[m][v], acc_nx[m][v], acc_nh[m][v] };
                    *(f32x4*)&lds[w][m][kg * 4 + v][c * 4] = pk;   // C/D: row=(l>>4)*4+v, col=l&15
                }
            __syncthreads();

            // ---- combine 8 wave-partials + pointwise: 1 item/thread ----
            float rr = 0.f, zz = 0.f, nx = 0.f, nh = 0.f;
#pragma unroll
            for (int ww = 0; ww < 8; ++ww) {
                f32x4 g = *(const f32x4*)&lds[ww][cm][cbr][jc * 4];
                rr += g[0]; zz += g[1]; nx += g[2]; nh += g[3];
            }
            const float r = sigm_(rr + bir + bhr);
            const float z = sigm_(zz + biz + bhz);
            const float n = tanh_((nx + bin) + r * (nh + bhn));
            const int bgl = b0 + cb;                       // global batch
            const long pofs = ((long)(LAYER * 2 + rp) * NB + bgl) * HID + j;
            const long nofs = ((long)(LAYER * 2 + wp) * NB + bgl) * HID + j;
            const float hp = hf[pofs];                     // block-private, cached
            const float hnew = (1.f - z) * hp + z * n;
            hf[nofs] = hnew;
            st_coh_u16(hb + nofs, f2bf(hnew));             // device-visible h state
            if (LAYER) out[((long)bgl * SEQ + st) * HID + j] = hnew;
        }

        if (i == SEQ) break;   // kernel-end sync covers the trailing memcpys

        // ---- grid barrier: flag stores + block-0 checker, zero atomics ----
        asm volatile("s_waitcnt vmcnt(0)" ::: "memory");   // hb write-through acked at L3
        __syncthreads();                                   // all threads' stores acked
        const unsigned tgt = (unsigned)(i + 1);
        if (tid == 0)
            __hip_atomic_store(flags + bid, tgt, __ATOMIC_RELAXED, __HIP_MEMORY_SCOPE_AGENT);
        if (bid == 0) {
            if (tid < 64) {
                bool ok;
                do {
                    unsigned f0 = __hip_atomic_load(flags + tid,       __ATOMIC_RELAXED, __HIP_MEMORY_SCOPE_AGENT);
                    unsigned f1 = __hip_atomic_load(flags + 64 + tid,  __ATOMIC_RELAXED, __HIP_MEMORY_SCOPE_AGENT);
                    unsigned f2 = __hip_atomic_load(flags + 128 + tid, __ATOMIC_RELAXED, __HIP_MEMORY_SCOPE_AGENT);
                    unsigned f3 = __hip_atomic_load(flags + 192 + tid, __ATOMIC_RELAXED, __HIP_MEMORY_SCOPE_AGENT);
                    ok = (f0 >= tgt) & (f1 >= tgt) & (f2 >= tgt) & (f3 >= tgt);
                } while (!__all(ok));
                if (tid < 8)
                    __hip_atomic_store(gens + tid * 16, tgt, __ATOMIC_RELAXED, __HIP_MEMORY_SCOPE_AGENT);
            }
            __syncthreads();
        } else {
            if (tid == 0) {
                while (__hip_atomic_load(gens + (bid & 7) * 16, __ATOMIC_RELAXED, __HIP_MEMORY_SCOPE_AGENT) < tgt)
                    __builtin_amdgcn_s_sleep(2);
            }
            __syncthreads();
        }
    }
}

__global__ __launch_bounds__(512, 2) void gru_persist(
    const unsigned short* __restrict__ xb,
    const unsigned short* __restrict__ W0i, const unsigned short* __restrict__ W0h,
    const unsigned short* __restrict__ W1i, const unsigned short* __restrict__ W1h,
    const float* __restrict__ bi0, const float* __restrict__ bh0,
    const float* __restrict__ bi1, const float* __restrict__ bh1,
    float* __restrict__ hf, unsigned short* __restrict__ hb,
    float* __restrict__ out, unsigned* __restrict__ bar)
{
    __shared__ float lds[8][2][16][68];   // [wave][m][row][16 cols x 4 gates + pad]
    const int bid = blockIdx.x;
    if (bid < 128) gru_loop<0>(xb, W0i, W0h, bi0, bh0, hf, hb, out, bar, bid, lds);
    else           gru_loop<1>(xb, W1i, W1h, bi1, bh1, hf, hb, out, bar, bid, lds);
}

__global__ __launch_bounds__(256) void cvt_bf16(const float* __restrict__ src,
                                                unsigned short* __restrict__ dst, int n4) {
    int i = blockIdx.x * 256 + threadIdx.x;
    if (i >= n4) return;
    float4 f = *(const float4*)(src + 4L * i);
    unsigned long long u =  (unsigned long long)f2bf(f.x)
                         | ((unsigned long long)f2bf(f.y) << 16)
                         | ((unsigned long long)f2bf(f.z) << 32)
                         | ((unsigned long long)f2bf(f.w) << 48);
    *(unsigned long long*)(dst + 4L * i) = u;
}

__global__ __launch_bounds__(256) void init_h(const float* __restrict__ h0,
                                              float* __restrict__ hf,
                                              unsigned short* __restrict__ hb) {
    int i = blockIdx.x * 256 + threadIdx.x;          // 2*64*1024 threads
    int layer = i >> 16, idx = i & 65535;
    float v = h0[i];
    hf[(long)(layer * 2 + 0) * 65536 + idx] = v;     // parity 0
    hb[(long)(layer * 2 + 0) * 65536 + idx] = f2bf(v);
}

extern "C" void kernel_launch(void* const* d_in, const int* in_sizes, int n_in,
                              void* d_out, int out_size, void* d_ws, size_t ws_size,
                              hipStream_t stream) {
    const float* x    = (const float*)d_in[0];
    const float* h0   = (const float*)d_in[1];
    const float* Wih0 = (const float*)d_in[2];
    const float* Whh0 = (const float*)d_in[3];
    const float* bih0 = (const float*)d_in[4];
    const float* bhh0 = (const float*)d_in[5];
    const float* Wih1 = (const float*)d_in[6];
    const float* Whh1 = (const float*)d_in[7];
    const float* bih1 = (const float*)d_in[8];
    const float* bhh1 = (const float*)d_in[9];

    float* out   = (float*)d_out;                    // [64][512][1024]
    float* hnout = out + (long)NB * SEQ * HID;       // [2][64][1024]

    // ws layout (~56 MiB):
    unsigned short* W0i = (unsigned short*)d_ws;             // [3072][512]
    unsigned short* W0h = W0i + 3072L * 512;                 // [3072][1024]
    unsigned short* W1i = W0h + 3072L * 1024;
    unsigned short* W1h = W1i + 3072L * 1024;
    float*          hf  = (float*)(W1h + 3072L * 1024);      // [2][2][64][1024] f32
    unsigned short* hb  = (unsigned short*)(hf + 4L * 65536);
    unsigned*       bar = (unsigned*)(hb + 4L * 65536);      // gens(8x16) + flags(256)
    unsigned short* xb  = (unsigned short*)(bar + 512);      // [64][512][512] bf16

    // gen lines + flags MUST be zero each call (ws is poisoned before timing)
    hipMemsetAsync(bar, 0, 2048, stream);

    cvt_bf16<<<(3072 * 512 / 4  + 255) / 256, 256, 0, stream>>>(Wih0, W0i, 3072 * 512 / 4);
    cvt_bf16<<<(3072 * 1024 / 4 + 255) / 256, 256, 0, stream>>>(Whh0, W0h, 3072 * 1024 / 4);
    cvt_bf16<<<(3072 * 1024 / 4 + 255) / 256, 256, 0, stream>>>(Wih1, W1i, 3072 * 1024 / 4);
    cvt_bf16<<<(3072 * 1024 / 4 + 255) / 256, 256, 0, stream>>>(Whh1, W1h, 3072 * 1024 / 4);
    cvt_bf16<<<(NB * SEQ * DIN0 / 4 + 255) / 256, 256, 0, stream>>>(x, xb, NB * SEQ * DIN0 / 4);
    init_h<<<512, 256, 0, stream>>>(h0, hf, hb);

    gru_persist<<<256, 512, 0, stream>>>(xb, W0i, W0h, W1i, W1h,
                                         bih0, bhh0, bih1, bhh1,
                                         hf, hb, out, bar);

    // both layers' t=511 state lands in parity 0
    hipMemcpyAsync(hnout,         hf,              65536 * sizeof(float),
                   hipMemcpyDeviceToDevice, stream);
    hipMemcpyAsync(hnout + 65536, hf + 2L * 65536, 65536 * sizeof(float),
                   hipMemcpyDeviceToDevice, stream);
}